// Round 3
// baseline (445.354 us; speedup 1.0000x reference)
//
#include <hip/hip_runtime.h>

#define SEQ   512
#define BATCH 4
#define NN    128
#define HID   64
#define G4    256   // 4*HID gates per layer
#define MAGIC 0x13579BDF

typedef _Float16 half2v __attribute__((ext_vector_type(2)));

// Fast activations: v_exp_f32 + v_rcp_f32 (abs err ~1e-6, threshold is 1e-3)
__device__ __forceinline__ float frcp(float x)  { return __builtin_amdgcn_rcpf(x); }
__device__ __forceinline__ float fsigm(float x) { return frcp(1.f + __expf(-x)); }
__device__ __forceinline__ float ftanh(float x) { return 1.f - 2.f * frcp(1.f + __expf(2.f * x)); }
__device__ __forceinline__ float lrelu(float x) { return x > 0.f ? x : 0.2f * x; }
__device__ __forceinline__ float dot4f(float4 w, float4 h) {
  return fmaf(w.x, h.x, fmaf(w.y, h.y, fmaf(w.z, h.z, w.w * h.w)));
}
__device__ __forceinline__ void pin4(float4& v) {
  asm volatile("" : "+v"(v.x), "+v"(v.y), "+v"(v.z), "+v"(v.w));
}
// Quad butterfly sum via self-inverse quad_perm: 0xB1={1,0,3,2}, 0x4E={2,3,0,1}.
__device__ __forceinline__ float qsum(float x) {
  x += __int_as_float(__builtin_amdgcn_update_dpp(
      0, __float_as_int(x), 0xB1, 0xF, 0xF, true));
  x += __int_as_float(__builtin_amdgcn_update_dpp(
      0, __float_as_int(x), 0x4E, 0xF, 0xF, true));
  return x;
}
__device__ __forceinline__ half2v u2h(unsigned u) {
  return __builtin_bit_cast(half2v, u);
}
// Pack two f32 -> f16x2 (RTZ packed cvt; ~0.5-ulp-of-f16 input quantization).
__device__ __forceinline__ half2v pk16(float lo, float hi) {
  return __builtin_bit_cast(half2v, __builtin_amdgcn_cvt_pkrtz(lo, hi));
}
// v_dot2_f32_f16: 2 f16 MACs, f32 accumulate (exact products, f32 sum).
__device__ __forceinline__ float fdot2(half2v a, half2v b, float c) {
#if __has_builtin(__builtin_amdgcn_fdot2)
  return __builtin_amdgcn_fdot2(a, b, c, false);
#else
  float d = c;
  asm("v_dot2_f32_f16 %0, %1, %2, %0" : "+v"(d) : "v"(a), "v"(b));
  return d;
#endif
}
// 16-elem f16 dot: 8 chained v_dot2 (w = 8 half2, h = two uint4 of packed f16).
__device__ __forceinline__ float dot8h(const half2v* w, const uint4& a,
                                       const uint4& b, float acc) {
  acc = fdot2(w[0], u2h(a.x), acc);
  acc = fdot2(w[1], u2h(a.y), acc);
  acc = fdot2(w[2], u2h(a.z), acc);
  acc = fdot2(w[3], u2h(a.w), acc);
  acc = fdot2(w[4], u2h(b.x), acc);
  acc = fdot2(w[5], u2h(b.y), acc);
  acc = fdot2(w[6], u2h(b.z), acc);
  acc = fdot2(w[7], u2h(b.w), acc);
  return acc;
}

// LDS-only barrier: s_waitcnt lgkmcnt(0) + s_barrier, NO vmcnt(0) drain.
#define BAR_LDS() asm volatile("s_waitcnt lgkmcnt(0)\n\ts_barrier" ::: "memory")

// ---------------------------------------------------------------------------
// fused_all: ONE kernel, 132 blocks x 768 threads.
//   blocks 0-3   : LSTM scan + heads, gated on banded X0 flags.
//   blocks 4-131 : X0 producer, band-interleaved; blocks 4-7 then GAT.
// R14: consumer matvecs moved to f16 v_dot2_f32_f16 (halves FMA issue) with
//   h stored packed f16x2 in LDS (halves ds_read_b128 count). Weights f16
//   (RTNE) in registers; X0/P1/state/activations stay f32. h-pair packing on
//   the write side via row_half_mirror DPP (lane 8k grabs neighbor-unit value
//   redundantly held by lane 8k+7), one ds_write_b32 per pair.
// ---------------------------------------------------------------------------
__global__ __attribute__((amdgpu_flat_work_group_size(768, 768),
                          amdgpu_waves_per_eu(3, 3)))
void fused_all(
    const float* __restrict__ x, const int* __restrict__ adj,
    const float* __restrict__ emb_w, const float* __restrict__ emb_b,
    const float* __restrict__ W1, const float* __restrict__ a1,
    const float* __restrict__ W2, const float* __restrict__ a2,
    const float* __restrict__ Wih0, const float* __restrict__ Whh0,
    const float* __restrict__ bih0, const float* __restrict__ bhh0,
    const float* __restrict__ Wih1, const float* __restrict__ Whh1,
    const float* __restrict__ bih1, const float* __restrict__ bhh1,
    const float* __restrict__ dw1, const float* __restrict__ db1,
    const float* __restrict__ dw2, const float* __restrict__ db2,
    const float* __restrict__ rw1, const float* __restrict__ rb1,
    const float* __restrict__ rw2, const float* __restrict__ rb2,
    const float* __restrict__ vw1, const float* __restrict__ vb1,
    const float* __restrict__ vw2, const float* __restrict__ vb2,
    float* __restrict__ X0T, float* __restrict__ xg,
    int* __restrict__ flags, float* __restrict__ out)
{
  const int bid = blockIdx.x;
  const int tid = threadIdx.x;

  if (bid >= 4) {
    // =================== PRODUCER: band-interleaved X0 ===================
    const int c = bid - 4;
    __shared__ __align__(16) float xls[NN];
    {
      const int g = tid >> 1, half = tid & 1;
      float4 w4[16];
      if (tid < 512) {
        const float4* wp = reinterpret_cast<const float4*>(Wih0 + g * NN + half * 64);
#pragma unroll
        for (int i = 0; i < 16; ++i) w4[i] = wp[i];
#pragma unroll
        for (int i = 0; i < 16; ++i) pin4(w4[i]);
      }
      const float bsum = (tid < 512) ? (bih0[g] + bhh0[g]) : 0.f;
      for (int phase = 0; phase < 4; ++phase) {
        const int T = c + 128 * phase;
        for (int bb = 0; bb < BATCH; ++bb) {
          if (tid < NN) xls[tid] = x[(bb * SEQ + T) * NN + tid];
          __syncthreads();
          if (tid < 512) {
            const float4* hp = reinterpret_cast<const float4*>(&xls[half * 64]);
            float p0 = 0.f, p1 = 0.f, p2 = 0.f, p3 = 0.f;
#pragma unroll
            for (int k = 0; k < 16; k += 4) {
              p0 += dot4f(w4[k],     hp[k]);
              p1 += dot4f(w4[k + 1], hp[k + 1]);
              p2 += dot4f(w4[k + 2], hp[k + 2]);
              p3 += dot4f(w4[k + 3], hp[k + 3]);
            }
            float p = (p0 + p1) + (p2 + p3);
            p += __shfl_xor(p, 1);
            if (half == 0)
              X0T[(4 * T + bb) * G4 + (g & 63) * 4 + (g >> 6)] = p + bsum;
          }
          __syncthreads();   // drains this block's X0 stores (vmcnt(0) before s_barrier)
        }
        if (tid == 0 && phase == 0)
          __hip_atomic_store(&flags[c], MAGIC, __ATOMIC_RELEASE,
                             __HIP_MEMORY_SCOPE_AGENT);
        if (tid == 0 && phase == 3)
          __hip_atomic_store(&flags[128 + c], MAGIC, __ATOMIC_RELEASE,
                             __HIP_MEMORY_SCOPE_AGENT);
      }
    }
    if (bid >= 8) return;

    // =================== GAT (blocks 4-7, batch b) ===================
    const int b = bid - 4;
    __shared__ float adjm[NN * 129];
    __shared__ __align__(16) float gxls[NN];
    __shared__ float u[16], v[16];
    __shared__ float Wh2[NN][9];
    __shared__ float f1b[NN], f2b[NN];
    __shared__ float p[NN];

    for (int idx = tid; idx < NN * NN; idx += 768)
      adjm[(idx >> 7) * 129 + (idx & 127)] = (adj[idx] > 0) ? 1.f : 0.f;
    if (tid < NN) gxls[tid] = x[(b * SEQ + (SEQ - 1)) * NN + tid];
    if (tid < 16) {
      float uu = 0.f, vv = 0.f;
      for (int fp = 0; fp < 16; ++fp) {
        uu += emb_w[fp] * W1[fp * 16 + tid];
        vv += emb_b[fp] * W1[fp * 16 + tid];
      }
      u[tid] = uu; v[tid] = vv;
    }
    __syncthreads();
    float s1 = 0.f, t1 = 0.f, s2 = 0.f, t2 = 0.f;
    for (int f = 0; f < 16; ++f) {
      s1 += u[f] * a1[f];      t1 += v[f] * a1[f];
      s2 += u[f] * a1[16 + f]; t2 += v[f] * a1[16 + f];
    }
    if (tid < NN) {
      const int i = tid;
      const float f1i = gxls[i] * s1 + t1;
      float m = -1e30f;
      for (int j = 0; j < NN; ++j)
        if (adjm[i * 129 + j] != 0.f)
          m = fmaxf(m, lrelu(f1i + gxls[j] * s2 + t2));
      float ssum = 0.f, ps = 0.f;
      for (int j = 0; j < NN; ++j)
        if (adjm[i * 129 + j] != 0.f) {
          const float wgt = __expf(lrelu(f1i + gxls[j] * s2 + t2) - m);
          ssum += wgt; ps += wgt * gxls[j];
        }
      p[i] = ps / ssum;
    }
    __syncthreads();
    if (tid < NN) {
      const int i = tid;
      float xg1[16];
#pragma unroll
      for (int f = 0; f < 16; ++f) {
        const float ov = p[i] * u[f] + v[f];
        xg1[f] = ov > 0.f ? ov : expm1f(ov);
      }
      float wrow[8];
#pragma unroll
      for (int f2 = 0; f2 < 8; ++f2) wrow[f2] = 0.f;
#pragma unroll
      for (int f = 0; f < 16; ++f) {
        const float xv = xg1[f];
#pragma unroll
        for (int f2 = 0; f2 < 8; ++f2) wrow[f2] += xv * W2[f * 8 + f2];
      }
      float fb1 = 0.f, fb2 = 0.f;
#pragma unroll
      for (int f2 = 0; f2 < 8; ++f2) {
        Wh2[i][f2] = wrow[f2];
        fb1 += wrow[f2] * a2[f2];
        fb2 += wrow[f2] * a2[8 + f2];
      }
      f1b[i] = fb1; f2b[i] = fb2;
    }
    __syncthreads();
    if (tid < NN) {
      const int i = tid;
      const float fi = f1b[i];
      float m = -1e30f;
      for (int j = 0; j < NN; ++j)
        if (adjm[i * 129 + j] != 0.f)
          m = fmaxf(m, lrelu(fi + f2b[j]));
      float ssum = 0.f;
      float o[8];
#pragma unroll
      for (int f2 = 0; f2 < 8; ++f2) o[f2] = 0.f;
      for (int j = 0; j < NN; ++j)
        if (adjm[i * 129 + j] != 0.f) {
          const float wgt = __expf(lrelu(fi + f2b[j]) - m);
          ssum += wgt;
#pragma unroll
          for (int f2 = 0; f2 < 8; ++f2) o[f2] += wgt * Wh2[j][f2];
        }
      const float inv = 1.f / ssum;
#pragma unroll
      for (int f2 = 0; f2 < 8; ++f2)
        xg[b * (NN * 8) + i * 8 + f2] = o[f2] * inv;
    }
    __syncthreads();
    if (tid == 0)
      __hip_atomic_store(&flags[256 + b], MAGIC, __ATOMIC_RELEASE,
                         __HIP_MEMORY_SCOPE_AGENT);
    return;
  }

  // =================== CONSUMER: LSTM scan + heads (blocks 0-3) ============
  const int b   = bid;
  const int t   = tid;
  const int grp = t >> 8;            // 0,1,2 (wave-aligned)
  const int r   = t & 255;           // == uu*4 + q2
  const int uu  = r >> 2, q2 = r & 3;

  // h stored packed f16x2, unit-pair per dword: hb16[buf][layer][unit>>1].
  __shared__ __align__(16) half2v hb16[2][2][HID / 2];
  __shared__ __align__(16) float P1[2][G4];       // dbuf ih-partials (f32)
  __shared__ float cbuf[1088];
  __shared__ float hidc[96];

  const float* Wsrc = (grp == 0) ? Whh0 : (grp == 1) ? Wih1 : Whh1;
  // f16 weights (RTNE via scalar cvt), 8 half2 per gate row-slice.
  half2v w16[4][8];
#pragma unroll
  for (int j = 0; j < 4; ++j) {
    const float* wr = Wsrc + (uu + 64 * j) * HID + 16 * q2;
#pragma unroll
    for (int c = 0; c < 4; ++c) {
      const float4 wv = *reinterpret_cast<const float4*>(wr + 4 * c);
      w16[j][2 * c]     = half2v{(_Float16)wv.x, (_Float16)wv.y};
      w16[j][2 * c + 1] = half2v{(_Float16)wv.z, (_Float16)wv.w};
    }
  }
  float4 b1v = make_float4(0.f, 0.f, 0.f, 0.f);
  if (grp == 2) {
    b1v.x = bih1[uu]       + bhh1[uu];
    b1v.y = bih1[uu + 64]  + bhh1[uu + 64];
    b1v.z = bih1[uu + 128] + bhh1[uu + 128];
    b1v.w = bih1[uu + 192] + bhh1[uu + 192];
  }

  if (t < 128) reinterpret_cast<unsigned*>(hb16)[t] = 0u;   // both bufs, both layers
  float cst = 0.f;
  const float* X0b = X0T + b * G4 + uu * 4;

  // Initial frontier: flags[0..31] (32-wide parallel acquire-RMW poll).
  int c_ok;
  {
    if (t < 32) {
      while (__hip_atomic_fetch_add(&flags[t], 0, __ATOMIC_ACQUIRE,
                                    __HIP_MEMORY_SCOPE_AGENT) != MAGIC) {}
    }
    __syncthreads();   // also makes hb16 zeroing visible
    c_ok = 31;
  }

  // Packed-h read pointers per RB parity: this thread's 16 h elems =
  // 8 half2 = 32 B at dword offset 8*q2 (two uint4 reads).
  const int lay = (grp == 2) ? 1 : 0;
  const uint4* hpA = reinterpret_cast<const uint4*>(&hb16[0][lay][0]) + 2 * q2;
  const uint4* hpB = reinterpret_cast<const uint4*>(&hb16[1][lay][0]) + 2 * q2;

  // 4-deep X0 prefetch in named registers (static indexing only).
  float4 xa0 = make_float4(0.f, 0.f, 0.f, 0.f), xa1 = xa0, xa2 = xa0, xa3 = xa0;
  if (grp == 0) {
    xa0 = *reinterpret_cast<const float4*>(X0b + 0 * (BATCH * G4));
    xa1 = *reinterpret_cast<const float4*>(X0b + 1 * (BATCH * G4));
    xa2 = *reinterpret_cast<const float4*>(X0b + 2 * (BATCH * G4));
    xa3 = *reinterpret_cast<const float4*>(X0b + 3 * (BATCH * G4));
  }

// h-pair pack: all 4 lanes of a quad hold the same unit's hv; row_half_mirror
// (0x141, self-inverse) gives lane 8k the value from lane 8k+7 = unit uu+1.
#define PACK_WRITE(LAYER, WB, HV)                                              \
  do {                                                                         \
    const float pr_ = __int_as_float(__builtin_amdgcn_update_dpp(              \
        0, __float_as_int(HV), 0x141, 0xF, 0xF, true));                        \
    if ((r & 7) == 0)                                                          \
      hb16[WB][LAYER][r >> 3] = pk16((HV), pr_);                               \
  } while (0)

#define LSTM_STEP(TT, RB, WB, XV)                                              \
  do {                                                                         \
    const uint4* hp = (RB) ? hpB : hpA;                                        \
    const uint4 ua = hp[0];                                                    \
    const uint4 ub = hp[1];                                                    \
    float4 p1v = make_float4(0.f, 0.f, 0.f, 0.f);                              \
    if (grp == 2) p1v = *reinterpret_cast<const float4*>(&P1[1 - (RB)][uu * 4]); \
    const float A0 = dot8h(w16[0], ua, ub, 0.f);                               \
    const float A1 = dot8h(w16[1], ua, ub, 0.f);                               \
    const float A2 = dot8h(w16[2], ua, ub, 0.f);                               \
    const float A3 = dot8h(w16[3], ua, ub, 0.f);                               \
    const float S0 = qsum(A0), S1 = qsum(A1), S2 = qsum(A2), S3 = qsum(A3);    \
    if (grp == 0) {                                                            \
      if ((TT) < SEQ) {                                                        \
        const float gi = fsigm(S0 + (XV).x);                                   \
        const float gf = fsigm(S1 + (XV).y);                                   \
        const float gg = ftanh(S2 + (XV).z);                                   \
        const float go = fsigm(S3 + (XV).w);                                   \
        cst = fmaf(gf, cst, gi * gg);                                          \
        const float hv = go * ftanh(cst);                                      \
        PACK_WRITE(0, WB, hv);                                                 \
      }                                                                        \
    } else if (grp == 1) {                                                     \
      if ((TT) >= 1 && (TT) <= SEQ) {                                          \
        const float sel = (q2 == 0) ? S0 : (q2 == 1) ? S1 : (q2 == 2) ? S2 : S3; \
        P1[RB][r] = sel;                                                       \
      }                                                                        \
    } else {                                                                   \
      if ((TT) >= 2) {                                                         \
        const float gi = fsigm(S0 + p1v.x + b1v.x);                            \
        const float gf = fsigm(S1 + p1v.y + b1v.y);                            \
        const float gg = ftanh(S2 + p1v.z + b1v.z);                            \
        const float go = fsigm(S3 + p1v.w + b1v.w);                            \
        cst = fmaf(gf, cst, gi * gg);                                          \
        const float hv = go * ftanh(cst);                                      \
        PACK_WRITE(1, WB, hv);                                                 \
      }                                                                        \
    }                                                                          \
    BAR_LDS();                                                                 \
  } while (0)

  for (int tt = 0; tt < SEQ; tt += 4) {   // steps TT = tt..tt+3
    // Frontier advance: 32-wide batch; keeps c_ok >= tt+35 > tt+7 (prefetch).
    if (tt + 36 > c_ok && c_ok < 255) {
      const int base = c_ok + 1;
      if (t < 32 && base + t <= 255) {
        while (__hip_atomic_fetch_add(&flags[base + t], 0, __ATOMIC_ACQUIRE,
                                      __HIP_MEMORY_SCOPE_AGENT) != MAGIC) {}
      }
      __syncthreads();
      c_ok = (base + 31 < 255) ? base + 31 : 255;
    }
#pragma unroll
    for (int j = 0; j < 4; ++j) {
      asm volatile("" : "+v"(w16[j][0]), "+v"(w16[j][1]), "+v"(w16[j][2]),
                        "+v"(w16[j][3]), "+v"(w16[j][4]), "+v"(w16[j][5]),
                        "+v"(w16[j][6]), "+v"(w16[j][7]));
    }
    // Issue next 4 X0 loads; they stay in flight across the BAR_LDS barriers.
    float4 xb0 = xa0, xb1 = xa1, xb2 = xa2, xb3 = xa3;
    if (grp == 0 && tt + 4 < SEQ) {
      xb0 = *reinterpret_cast<const float4*>(X0b + (tt + 4) * (BATCH * G4));
      xb1 = *reinterpret_cast<const float4*>(X0b + (tt + 5) * (BATCH * G4));
      xb2 = *reinterpret_cast<const float4*>(X0b + (tt + 6) * (BATCH * G4));
      xb3 = *reinterpret_cast<const float4*>(X0b + (tt + 7) * (BATCH * G4));
    }
    LSTM_STEP(tt + 0, 0, 1, xa0);
    LSTM_STEP(tt + 1, 1, 0, xa1);
    LSTM_STEP(tt + 2, 0, 1, xa2);
    LSTM_STEP(tt + 3, 1, 0, xa3);
    xa0 = xb0; xa1 = xb1; xa2 = xb2; xa3 = xb3;
  }
  // Pipeline drain: TT = 512, 513 (grp0 inactive; XV unused).
  LSTM_STEP(512, 0, 1, xa0);
  LSTM_STEP(513, 1, 0, xa1);
#undef LSTM_STEP
#undef PACK_WRITE
  // grp2's last write (TT=513, WB=0): hb16[0][1][*] = h1[SEQ-1] = xl_out.

  // wait for this batch's GAT result
  if (t == 0) {
    while (__hip_atomic_fetch_add(&flags[256 + b], 0, __ATOMIC_ACQUIRE,
                                  __HIP_MEMORY_SCOPE_AGENT) != MAGIC) {}
  }
  __syncthreads();

  // ---------------- fused heads: c = [h1(64) | xg_b(1024)] ----------------
  if (t < 64) {
    const _Float16* hh = reinterpret_cast<const _Float16*>(&hb16[0][1][0]);
    cbuf[t] = (float)hh[t];
  }
  for (int k = t; k < 1024; k += 768) cbuf[64 + k] = xg[b * 1024 + k];
  __syncthreads();
  if (t < 96) {
    const int head = t >> 5, h = t & 31;
    const float* w1 = (head == 0) ? dw1 : (head == 1) ? rw1 : vw1;
    const float* b1 = (head == 0) ? db1 : (head == 1) ? rb1 : vb1;
    float a0 = 0.f, a1v = 0.f, a2v = 0.f, a3v = 0.f;
    for (int k = 0; k < 1088; k += 4) {
      a0  = fmaf(cbuf[k],     w1[k * 32 + h],       a0);
      a1v = fmaf(cbuf[k + 1], w1[(k + 1) * 32 + h], a1v);
      a2v = fmaf(cbuf[k + 2], w1[(k + 2) * 32 + h], a2v);
      a3v = fmaf(cbuf[k + 3], w1[(k + 3) * 32 + h], a3v);
    }
    hidc[head * 32 + h] = fmaxf(b1[h] + ((a0 + a1v) + (a2v + a3v)), 0.f);
  }
  __syncthreads();
  if (t < 4) {
    const int head2 = (t < 2) ? t : 2;
    const int o = (t < 2) ? 0 : (t - 2);
    const int odim = (t < 2) ? 1 : 2;
    const float* w2  = (head2 == 0) ? dw2 : (head2 == 1) ? rw2 : vw2;
    const float* b2p = (head2 == 0) ? db2 : (head2 == 1) ? rb2 : vb2;
    float acc = b2p[o];
    for (int hh = 0; hh < 32; ++hh)
      acc = fmaf(hidc[head2 * 32 + hh], w2[hh * odim + o], acc);
    const int off = (t == 0) ? b : (t == 1) ? (4 + b) : (8 + 2 * b + o);
    out[off] = acc;   // [dir(4) | ret(4) | vol(4x2)] flat
  }
}

// ---------------------------------------------------------------------------
extern "C" void kernel_launch(void* const* d_in, const int* in_sizes, int n_in,
                              void* d_out, int out_size, void* d_ws, size_t ws_size,
                              hipStream_t stream) {
  const float* x     = (const float*)d_in[0];
  const int*   adj   = (const int*)  d_in[1];
  const float* emb_w = (const float*)d_in[2];
  const float* emb_b = (const float*)d_in[3];
  const float* g1W   = (const float*)d_in[4];
  const float* g1a   = (const float*)d_in[5];
  const float* g2W   = (const float*)d_in[6];
  const float* g2a   = (const float*)d_in[7];
  const float* Wih0  = (const float*)d_in[8];
  const float* Whh0  = (const float*)d_in[9];
  const float* bih0  = (const float*)d_in[10];
  const float* bhh0  = (const float*)d_in[11];
  const float* Wih1  = (const float*)d_in[12];
  const float* Whh1  = (const float*)d_in[13];
  const float* bih1  = (const float*)d_in[14];
  const float* bhh1  = (const float*)d_in[15];
  const float* dw1 = (const float*)d_in[16]; const float* db1 = (const float*)d_in[17];
  const float* dw2 = (const float*)d_in[18]; const float* db2 = (const float*)d_in[19];
  const float* rw1 = (const float*)d_in[20]; const float* rb1 = (const float*)d_in[21];
  const float* rw2 = (const float*)d_in[22]; const float* rb2 = (const float*)d_in[23];
  const float* vw1 = (const float*)d_in[24]; const float* vb1 = (const float*)d_in[25];
  const float* vw2 = (const float*)d_in[26]; const float* vb2 = (const float*)d_in[27];

  float* ws = (float*)d_ws;
  float* X0 = ws;                          // SEQ*BATCH*256 floats = 2 MB (transposed)
  float* xg = ws + SEQ * BATCH * G4;       // 4096 floats
  int*  flg = (int*)(xg + BATCH * NN * 8); // 260 flag ints (0xAA-poison = not ready)
  float* out = (float*)d_out;

  hipLaunchKernelGGL(fused_all, dim3(132), dim3(768), 0, stream,
                     x, adj, emb_w, emb_b, g1W, g1a, g2W, g2a,
                     Wih0, Whh0, bih0, bhh0, Wih1, Whh1, bih1, bhh1,
                     dw1, db1, dw2, db2, rw1, rb1, rw2, rb2,
                     vw1, vb1, vw2, vb2,
                     X0, xg, flg, out);
}

// Round 5
// 412.830 us; speedup vs baseline: 1.0788x; 1.0788x over previous
//
#include <hip/hip_runtime.h>

#define SEQ   512
#define BATCH 4
#define NN    128
#define HID   64
#define G4    256   // 4*HID gates per layer
#define MAGIC 0x13579BDF

typedef _Float16 half2v __attribute__((ext_vector_type(2)));

// Fast activations: v_exp_f32 + v_rcp_f32 (abs err ~1e-6, threshold is 1e-3)
__device__ __forceinline__ float frcp(float x)  { return __builtin_amdgcn_rcpf(x); }
__device__ __forceinline__ float fsigm(float x) { return frcp(1.f + __expf(-x)); }
__device__ __forceinline__ float ftanh(float x) { return 1.f - 2.f * frcp(1.f + __expf(2.f * x)); }
__device__ __forceinline__ float lrelu(float x) { return x > 0.f ? x : 0.2f * x; }
__device__ __forceinline__ float dot4f(float4 w, float4 h) {
  return fmaf(w.x, h.x, fmaf(w.y, h.y, fmaf(w.z, h.z, w.w * h.w)));
}
__device__ __forceinline__ void pin4(float4& v) {
  asm volatile("" : "+v"(v.x), "+v"(v.y), "+v"(v.z), "+v"(v.w));
}
// Quad butterfly sum via self-inverse quad_perm: 0xB1={1,0,3,2}, 0x4E={2,3,0,1}.
__device__ __forceinline__ float qsum(float x) {
  x += __int_as_float(__builtin_amdgcn_update_dpp(
      0, __float_as_int(x), 0xB1, 0xF, 0xF, true));
  x += __int_as_float(__builtin_amdgcn_update_dpp(
      0, __float_as_int(x), 0x4E, 0xF, 0xF, true));
  return x;
}
__device__ __forceinline__ half2v u2h(unsigned u) {
  return __builtin_bit_cast(half2v, u);
}
// Pack two f32 -> f16x2 (RTZ packed cvt).
__device__ __forceinline__ half2v pk16(float lo, float hi) {
  return __builtin_bit_cast(half2v, __builtin_amdgcn_cvt_pkrtz(lo, hi));
}
// v_dot2_f32_f16: 2 f16 MACs, f32 accumulate (exact products, f32 sum).
__device__ __forceinline__ float fdot2(half2v a, half2v b, float c) {
#if __has_builtin(__builtin_amdgcn_fdot2)
  return __builtin_amdgcn_fdot2(a, b, c, false);
#else
  float d = c;
  asm("v_dot2_f32_f16 %0, %1, %2, %0" : "+v"(d) : "v"(a), "v"(b));
  return d;
#endif
}
// 16-elem f16 dot: 8 chained v_dot2 (w = 8 half2, h = two uint4 of packed f16).
__device__ __forceinline__ float dot8h(const half2v* w, const uint4& a,
                                       const uint4& b, float acc) {
  acc = fdot2(w[0], u2h(a.x), acc);
  acc = fdot2(w[1], u2h(a.y), acc);
  acc = fdot2(w[2], u2h(a.z), acc);
  acc = fdot2(w[3], u2h(a.w), acc);
  acc = fdot2(w[4], u2h(b.x), acc);
  acc = fdot2(w[5], u2h(b.y), acc);
  acc = fdot2(w[6], u2h(b.z), acc);
  acc = fdot2(w[7], u2h(b.w), acc);
  return acc;
}

// LDS-only barrier: s_waitcnt lgkmcnt(0) + s_barrier, NO vmcnt(0) drain.
#define BAR_LDS() asm volatile("s_waitcnt lgkmcnt(0)\n\ts_barrier" ::: "memory")

// ---------------------------------------------------------------------------
// fused_all: ONE kernel, 132 blocks x 256 threads.
//   blocks 0-3   : LSTM scan + heads, gated on banded X0 flags.
//   blocks 4-131 : X0 producer, band-interleaved; blocks 4-7 then GAT.
// R16 = R15 with the layer-1 off-by-one FIXED: layer 1 at step TT consumes
//   B = Wih1*h0[TT-1] computed THIS step (same h0 LDS read), not a stale
//   register-carried copy. One-stage pipeline: step TT produces h0[TT] and
//   h1[TT-1]; drain step TT=512 produces h1[511] into hb16[1][1].
// ---------------------------------------------------------------------------
__global__ __attribute__((amdgpu_flat_work_group_size(256, 256),
                          amdgpu_waves_per_eu(1, 4)))
void fused_all(
    const float* __restrict__ x, const int* __restrict__ adj,
    const float* __restrict__ emb_w, const float* __restrict__ emb_b,
    const float* __restrict__ W1, const float* __restrict__ a1,
    const float* __restrict__ W2, const float* __restrict__ a2,
    const float* __restrict__ Wih0, const float* __restrict__ Whh0,
    const float* __restrict__ bih0, const float* __restrict__ bhh0,
    const float* __restrict__ Wih1, const float* __restrict__ Whh1,
    const float* __restrict__ bih1, const float* __restrict__ bhh1,
    const float* __restrict__ dw1, const float* __restrict__ db1,
    const float* __restrict__ dw2, const float* __restrict__ db2,
    const float* __restrict__ rw1, const float* __restrict__ rb1,
    const float* __restrict__ rw2, const float* __restrict__ rb2,
    const float* __restrict__ vw1, const float* __restrict__ vb1,
    const float* __restrict__ vw2, const float* __restrict__ vb2,
    float* __restrict__ X0T, float* __restrict__ xg,
    int* __restrict__ flags, float* __restrict__ out)
{
  const int bid = blockIdx.x;
  const int tid = threadIdx.x;

  if (bid >= 4) {
    // =================== PRODUCER: band-interleaved X0 ===================
    const int c = bid - 4;
    __shared__ __align__(16) float xls[NN];
    {
      const int g = tid;                       // one gate per thread
      float4 w4[32];
      {
        const float4* wp = reinterpret_cast<const float4*>(Wih0 + g * NN);
#pragma unroll
        for (int i = 0; i < 32; ++i) w4[i] = wp[i];
#pragma unroll
        for (int i = 0; i < 32; ++i) pin4(w4[i]);
      }
      const float bsum = bih0[g] + bhh0[g];
      for (int phase = 0; phase < 4; ++phase) {
        const int T = c + 128 * phase;
        for (int bb = 0; bb < BATCH; ++bb) {
          if (tid < NN) xls[tid] = x[(bb * SEQ + T) * NN + tid];
          __syncthreads();
          {
            const float4* hp = reinterpret_cast<const float4*>(xls);
            float p0 = 0.f, p1 = 0.f, p2 = 0.f, p3 = 0.f;
#pragma unroll
            for (int k = 0; k < 32; k += 4) {
              p0 += dot4f(w4[k],     hp[k]);
              p1 += dot4f(w4[k + 1], hp[k + 1]);
              p2 += dot4f(w4[k + 2], hp[k + 2]);
              p3 += dot4f(w4[k + 3], hp[k + 3]);
            }
            X0T[(4 * T + bb) * G4 + (g & 63) * 4 + (g >> 6)] =
                ((p0 + p1) + (p2 + p3)) + bsum;
          }
          __syncthreads();   // drains this block's X0 stores before flag release
        }
        if (tid == 0 && phase == 0)
          __hip_atomic_store(&flags[c], MAGIC, __ATOMIC_RELEASE,
                             __HIP_MEMORY_SCOPE_AGENT);
        if (tid == 0 && phase == 3)
          __hip_atomic_store(&flags[128 + c], MAGIC, __ATOMIC_RELEASE,
                             __HIP_MEMORY_SCOPE_AGENT);
      }
    }
    if (bid >= 8) return;

    // =================== GAT (blocks 4-7, batch b) ===================
    const int b = bid - 4;
    __shared__ float adjm[NN * 129];
    __shared__ __align__(16) float gxls[NN];
    __shared__ float u[16], v[16];
    __shared__ float Wh2[NN][9];
    __shared__ float f1b[NN], f2b[NN];
    __shared__ float p[NN];

    for (int idx = tid; idx < NN * NN; idx += 256)
      adjm[(idx >> 7) * 129 + (idx & 127)] = (adj[idx] > 0) ? 1.f : 0.f;
    if (tid < NN) gxls[tid] = x[(b * SEQ + (SEQ - 1)) * NN + tid];
    if (tid < 16) {
      float uu = 0.f, vv = 0.f;
      for (int fp = 0; fp < 16; ++fp) {
        uu += emb_w[fp] * W1[fp * 16 + tid];
        vv += emb_b[fp] * W1[fp * 16 + tid];
      }
      u[tid] = uu; v[tid] = vv;
    }
    __syncthreads();
    float s1 = 0.f, t1 = 0.f, s2 = 0.f, t2 = 0.f;
    for (int f = 0; f < 16; ++f) {
      s1 += u[f] * a1[f];      t1 += v[f] * a1[f];
      s2 += u[f] * a1[16 + f]; t2 += v[f] * a1[16 + f];
    }
    if (tid < NN) {
      const int i = tid;
      const float f1i = gxls[i] * s1 + t1;
      float m = -1e30f;
      for (int j = 0; j < NN; ++j)
        if (adjm[i * 129 + j] != 0.f)
          m = fmaxf(m, lrelu(f1i + gxls[j] * s2 + t2));
      float ssum = 0.f, ps = 0.f;
      for (int j = 0; j < NN; ++j)
        if (adjm[i * 129 + j] != 0.f) {
          const float wgt = __expf(lrelu(f1i + gxls[j] * s2 + t2) - m);
          ssum += wgt; ps += wgt * gxls[j];
        }
      p[i] = ps / ssum;
    }
    __syncthreads();
    if (tid < NN) {
      const int i = tid;
      float xg1[16];
#pragma unroll
      for (int f = 0; f < 16; ++f) {
        const float ov = p[i] * u[f] + v[f];
        xg1[f] = ov > 0.f ? ov : expm1f(ov);
      }
      float wrow[8];
#pragma unroll
      for (int f2 = 0; f2 < 8; ++f2) wrow[f2] = 0.f;
#pragma unroll
      for (int f = 0; f < 16; ++f) {
        const float xv = xg1[f];
#pragma unroll
        for (int f2 = 0; f2 < 8; ++f2) wrow[f2] += xv * W2[f * 8 + f2];
      }
      float fb1 = 0.f, fb2 = 0.f;
#pragma unroll
      for (int f2 = 0; f2 < 8; ++f2) {
        Wh2[i][f2] = wrow[f2];
        fb1 += wrow[f2] * a2[f2];
        fb2 += wrow[f2] * a2[8 + f2];
      }
      f1b[i] = fb1; f2b[i] = fb2;
    }
    __syncthreads();
    if (tid < NN) {
      const int i = tid;
      const float fi = f1b[i];
      float m = -1e30f;
      for (int j = 0; j < NN; ++j)
        if (adjm[i * 129 + j] != 0.f)
          m = fmaxf(m, lrelu(fi + f2b[j]));
      float ssum = 0.f;
      float o[8];
#pragma unroll
      for (int f2 = 0; f2 < 8; ++f2) o[f2] = 0.f;
      for (int j = 0; j < NN; ++j)
        if (adjm[i * 129 + j] != 0.f) {
          const float wgt = __expf(lrelu(fi + f2b[j]) - m);
          ssum += wgt;
#pragma unroll
          for (int f2 = 0; f2 < 8; ++f2) o[f2] += wgt * Wh2[j][f2];
        }
      const float inv = 1.f / ssum;
#pragma unroll
      for (int f2 = 0; f2 < 8; ++f2)
        xg[b * (NN * 8) + i * 8 + f2] = o[f2] * inv;
    }
    __syncthreads();
    if (tid == 0)
      __hip_atomic_store(&flags[256 + b], MAGIC, __ATOMIC_RELEASE,
                         __HIP_MEMORY_SCOPE_AGENT);
    return;
  }

  // =================== CONSUMER: LSTM scan + heads (blocks 0-3) ============
  // 256 threads = 4 waves, one per SIMD. Thread (uu, q2) owns the q2-th
  // 16-col quarter of gates {uu, uu+64, uu+128, uu+192} for ALL THREE
  // matvecs (A=Whh0*h0, B=Wih1*h0, C=Whh1*h1). At step TT: produce h0[TT]
  // (from A + X0[TT]) and h1[TT-1] (from B + C), both from the SAME h0
  // read h0[TT-1]. No register carry across steps (R15 bug removed).
  const int b   = bid;
  const int t   = tid;
  const int uu  = t >> 2, q2 = t & 3;
  const int r   = t;

  // h stored packed f16x2, unit-pair per dword: hb16[buf][layer][unit>>1].
  __shared__ __align__(16) half2v hb16[2][2][HID / 2];
  __shared__ float cbuf[1088];
  __shared__ float hidc[96];

  // f16 weight slices: [matvec][gate][8 half2]. 96 VGPRs.
  half2v wA[4][8], wB[4][8], wC[4][8];
#pragma unroll
  for (int j = 0; j < 4; ++j) {
    const int row = (uu + 64 * j) * HID + 16 * q2;
    const float* wa = Whh0 + row;
    const float* wb = Wih1 + row;
    const float* wc = Whh1 + row;
#pragma unroll
    for (int c = 0; c < 4; ++c) {
      const float4 va = *reinterpret_cast<const float4*>(wa + 4 * c);
      const float4 vb = *reinterpret_cast<const float4*>(wb + 4 * c);
      const float4 vc = *reinterpret_cast<const float4*>(wc + 4 * c);
      wA[j][2 * c]     = half2v{(_Float16)va.x, (_Float16)va.y};
      wA[j][2 * c + 1] = half2v{(_Float16)va.z, (_Float16)va.w};
      wB[j][2 * c]     = half2v{(_Float16)vb.x, (_Float16)vb.y};
      wB[j][2 * c + 1] = half2v{(_Float16)vb.z, (_Float16)vb.w};
      wC[j][2 * c]     = half2v{(_Float16)vc.x, (_Float16)vc.y};
      wC[j][2 * c + 1] = half2v{(_Float16)vc.z, (_Float16)vc.w};
    }
  }
  float4 b1v;
  b1v.x = bih1[uu]       + bhh1[uu];
  b1v.y = bih1[uu + 64]  + bhh1[uu + 64];
  b1v.z = bih1[uu + 128] + bhh1[uu + 128];
  b1v.w = bih1[uu + 192] + bhh1[uu + 192];

  if (t < 128) reinterpret_cast<unsigned*>(hb16)[t] = 0u;   // both bufs+layers
  float cst0 = 0.f, cst1 = 0.f;
  const float* X0b = X0T + b * G4 + uu * 4;

  // Initial frontier: flags[0..31] (32-wide parallel acquire-RMW poll).
  int c_ok;
  {
    if (t < 32) {
      while (__hip_atomic_fetch_add(&flags[t], 0, __ATOMIC_ACQUIRE,
                                    __HIP_MEMORY_SCOPE_AGENT) != MAGIC) {}
    }
    __syncthreads();   // also makes hb16 zeroing visible
    c_ok = 31;
  }

  // Packed-h read pointers per RB parity (thread's 16 elems = 32 B at dword
  // offset 8*q2 -> two uint4 reads per layer).
  const uint4* h0A = reinterpret_cast<const uint4*>(&hb16[0][0][0]) + 2 * q2;
  const uint4* h0B = reinterpret_cast<const uint4*>(&hb16[1][0][0]) + 2 * q2;
  const uint4* h1A = reinterpret_cast<const uint4*>(&hb16[0][1][0]) + 2 * q2;
  const uint4* h1B = reinterpret_cast<const uint4*>(&hb16[1][1][0]) + 2 * q2;

  // 4-deep X0 prefetch in named registers (static indexing only).
  float4 xa0 = *reinterpret_cast<const float4*>(X0b + 0 * (BATCH * G4));
  float4 xa1 = *reinterpret_cast<const float4*>(X0b + 1 * (BATCH * G4));
  float4 xa2 = *reinterpret_cast<const float4*>(X0b + 2 * (BATCH * G4));
  float4 xa3 = *reinterpret_cast<const float4*>(X0b + 3 * (BATCH * G4));

// h-pair pack: all 4 lanes of a quad hold the same unit's hv; row_half_mirror
// (0x141, self-inverse) gives lane 8k the value from lane 8k+7 = unit uu+1.
#define PACK_WRITE(LAYER, WB, HV)                                              \
  do {                                                                         \
    const float pr_ = __int_as_float(__builtin_amdgcn_update_dpp(              \
        0, __float_as_int(HV), 0x141, 0xF, 0xF, true));                        \
    if ((r & 7) == 0)                                                          \
      hb16[WB][LAYER][r >> 3] = pk16((HV), pr_);                               \
  } while (0)

// At macro step TT: read h0[TT-1] and h1[TT-2] from buffer RB. Produce
// h0[TT] (layer0: A + X0[TT]) and h1[TT-1] (layer1: B + C, both current-
// step sums) into buffer WB.
#define LSTM_STEP(TT, RB, WB, XV)                                              \
  do {                                                                         \
    const uint4* h0p = (RB) ? h0B : h0A;                                       \
    const uint4* h1p = (RB) ? h1B : h1A;                                       \
    const uint4 ha = h0p[0], hbb = h0p[1];                                     \
    const uint4 ga = h1p[0], gbb = h1p[1];                                     \
    float A0 = dot8h(wA[0], ha, hbb, 0.f);                                     \
    float A1 = dot8h(wA[1], ha, hbb, 0.f);                                     \
    float A2 = dot8h(wA[2], ha, hbb, 0.f);                                     \
    float A3 = dot8h(wA[3], ha, hbb, 0.f);                                     \
    float B0 = dot8h(wB[0], ha, hbb, 0.f);                                     \
    float B1 = dot8h(wB[1], ha, hbb, 0.f);                                     \
    float B2 = dot8h(wB[2], ha, hbb, 0.f);                                     \
    float B3 = dot8h(wB[3], ha, hbb, 0.f);                                     \
    float C0 = dot8h(wC[0], ga, gbb, 0.f);                                     \
    float C1 = dot8h(wC[1], ga, gbb, 0.f);                                     \
    float C2 = dot8h(wC[2], ga, gbb, 0.f);                                     \
    float C3 = dot8h(wC[3], ga, gbb, 0.f);                                     \
    const float SA0 = qsum(A0), SA1 = qsum(A1), SA2 = qsum(A2), SA3 = qsum(A3);\
    if ((TT) < SEQ) {                                                          \
      const float gi = fsigm(SA0 + (XV).x);                                    \
      const float gf = fsigm(SA1 + (XV).y);                                    \
      const float gg = ftanh(SA2 + (XV).z);                                    \
      const float go = fsigm(SA3 + (XV).w);                                    \
      cst0 = fmaf(gf, cst0, gi * gg);                                          \
      const float hv = go * ftanh(cst0);                                       \
      PACK_WRITE(0, WB, hv);                                                   \
    }                                                                          \
    const float SB0 = qsum(B0), SB1 = qsum(B1), SB2 = qsum(B2), SB3 = qsum(B3);\
    const float SC0 = qsum(C0), SC1 = qsum(C1), SC2 = qsum(C2), SC3 = qsum(C3);\
    if ((TT) >= 1) {                                                           \
      const float gi = fsigm(SC0 + SB0 + b1v.x);                               \
      const float gf = fsigm(SC1 + SB1 + b1v.y);                               \
      const float gg = ftanh(SC2 + SB2 + b1v.z);                               \
      const float go = fsigm(SC3 + SB3 + b1v.w);                               \
      cst1 = fmaf(gf, cst1, gi * gg);                                          \
      const float hv = go * ftanh(cst1);                                       \
      PACK_WRITE(1, WB, hv);                                                   \
    }                                                                          \
    BAR_LDS();                                                                 \
  } while (0)

  for (int tt = 0; tt < SEQ; tt += 4) {   // steps TT = tt..tt+3
    // Frontier advance: 32-wide batch; keeps c_ok >= tt+35 > tt+7 (prefetch).
    if (tt + 36 > c_ok && c_ok < 255) {
      const int base = c_ok + 1;
      if (t < 32 && base + t <= 255) {
        while (__hip_atomic_fetch_add(&flags[base + t], 0, __ATOMIC_ACQUIRE,
                                      __HIP_MEMORY_SCOPE_AGENT) != MAGIC) {}
      }
      __syncthreads();
      c_ok = (base + 31 < 255) ? base + 31 : 255;
    }
#pragma unroll
    for (int j = 0; j < 4; ++j) {
      asm volatile("" : "+v"(wA[j][0]), "+v"(wA[j][1]), "+v"(wA[j][2]),
                        "+v"(wA[j][3]), "+v"(wA[j][4]), "+v"(wA[j][5]),
                        "+v"(wA[j][6]), "+v"(wA[j][7]));
      asm volatile("" : "+v"(wB[j][0]), "+v"(wB[j][1]), "+v"(wB[j][2]),
                        "+v"(wB[j][3]), "+v"(wB[j][4]), "+v"(wB[j][5]),
                        "+v"(wB[j][6]), "+v"(wB[j][7]));
      asm volatile("" : "+v"(wC[j][0]), "+v"(wC[j][1]), "+v"(wC[j][2]),
                        "+v"(wC[j][3]), "+v"(wC[j][4]), "+v"(wC[j][5]),
                        "+v"(wC[j][6]), "+v"(wC[j][7]));
    }
    // Issue next 4 X0 loads; they stay in flight across the BAR_LDS barriers.
    float4 xb0 = xa0, xb1 = xa1, xb2 = xa2, xb3 = xa3;
    if (tt + 4 < SEQ) {
      xb0 = *reinterpret_cast<const float4*>(X0b + (tt + 4) * (BATCH * G4));
      xb1 = *reinterpret_cast<const float4*>(X0b + (tt + 5) * (BATCH * G4));
      xb2 = *reinterpret_cast<const float4*>(X0b + (tt + 6) * (BATCH * G4));
      xb3 = *reinterpret_cast<const float4*>(X0b + (tt + 7) * (BATCH * G4));
    }
    LSTM_STEP(tt + 0, 0, 1, xa0);
    LSTM_STEP(tt + 1, 1, 0, xa1);
    LSTM_STEP(tt + 2, 0, 1, xa2);
    LSTM_STEP(tt + 3, 1, 0, xa3);
    xa0 = xb0; xa1 = xb1; xa2 = xb2; xa3 = xb3;
  }
  // Drain: TT = SEQ produces h1[SEQ-1] into buffer WB=1 (layer0 off).
  LSTM_STEP(512, 0, 1, xa0);
#undef LSTM_STEP
#undef PACK_WRITE
  // xl_out = h1[SEQ-1] = hb16[1][1][*].

  // wait for this batch's GAT result
  if (t == 0) {
    while (__hip_atomic_fetch_add(&flags[256 + b], 0, __ATOMIC_ACQUIRE,
                                  __HIP_MEMORY_SCOPE_AGENT) != MAGIC) {}
  }
  __syncthreads();

  // ---------------- fused heads: c = [h1(64) | xg_b(1024)] ----------------
  if (t < 64) {
    const _Float16* hh = reinterpret_cast<const _Float16*>(&hb16[1][1][0]);
    cbuf[t] = (float)hh[t];
  }
  for (int k = t; k < 1024; k += 256) cbuf[64 + k] = xg[b * 1024 + k];
  __syncthreads();
  if (t < 96) {
    const int head = t >> 5, h = t & 31;
    const float* w1 = (head == 0) ? dw1 : (head == 1) ? rw1 : vw1;
    const float* b1 = (head == 0) ? db1 : (head == 1) ? rb1 : vb1;
    float a0 = 0.f, a1v = 0.f, a2v = 0.f, a3v = 0.f;
    for (int k = 0; k < 1088; k += 4) {
      a0  = fmaf(cbuf[k],     w1[k * 32 + h],       a0);
      a1v = fmaf(cbuf[k + 1], w1[(k + 1) * 32 + h], a1v);
      a2v = fmaf(cbuf[k + 2], w1[(k + 2) * 32 + h], a2v);
      a3v = fmaf(cbuf[k + 3], w1[(k + 3) * 32 + h], a3v);
    }
    hidc[head * 32 + h] = fmaxf(b1[h] + ((a0 + a1v) + (a2v + a3v)), 0.f);
  }
  __syncthreads();
  if (t < 4) {
    const int head2 = (t < 2) ? t : 2;
    const int o = (t < 2) ? 0 : (t - 2);
    const int odim = (t < 2) ? 1 : 2;
    const float* w2  = (head2 == 0) ? dw2 : (head2 == 1) ? rw2 : vw2;
    const float* b2p = (head2 == 0) ? db2 : (head2 == 1) ? rb2 : vb2;
    float acc = b2p[o];
    for (int hh = 0; hh < 32; ++hh)
      acc = fmaf(hidc[head2 * 32 + hh], w2[hh * odim + o], acc);
    const int off = (t == 0) ? b : (t == 1) ? (4 + b) : (8 + 2 * b + o);
    out[off] = acc;   // [dir(4) | ret(4) | vol(4x2)] flat
  }
}

// ---------------------------------------------------------------------------
extern "C" void kernel_launch(void* const* d_in, const int* in_sizes, int n_in,
                              void* d_out, int out_size, void* d_ws, size_t ws_size,
                              hipStream_t stream) {
  const float* x     = (const float*)d_in[0];
  const int*   adj   = (const int*)  d_in[1];
  const float* emb_w = (const float*)d_in[2];
  const float* emb_b = (const float*)d_in[3];
  const float* g1W   = (const float*)d_in[4];
  const float* g1a   = (const float*)d_in[5];
  const float* g2W   = (const float*)d_in[6];
  const float* g2a   = (const float*)d_in[7];
  const float* Wih0  = (const float*)d_in[8];
  const float* Whh0  = (const float*)d_in[9];
  const float* bih0  = (const float*)d_in[10];
  const float* bhh0  = (const float*)d_in[11];
  const float* Wih1  = (const float*)d_in[12];
  const float* Whh1  = (const float*)d_in[13];
  const float* bih1  = (const float*)d_in[14];
  const float* bhh1  = (const float*)d_in[15];
  const float* dw1 = (const float*)d_in[16]; const float* db1 = (const float*)d_in[17];
  const float* dw2 = (const float*)d_in[18]; const float* db2 = (const float*)d_in[19];
  const float* rw1 = (const float*)d_in[20]; const float* rb1 = (const float*)d_in[21];
  const float* rw2 = (const float*)d_in[22]; const float* rb2 = (const float*)d_in[23];
  const float* vw1 = (const float*)d_in[24]; const float* vb1 = (const float*)d_in[25];
  const float* vw2 = (const float*)d_in[26]; const float* vb2 = (const float*)d_in[27];

  float* ws = (float*)d_ws;
  float* X0 = ws;                          // SEQ*BATCH*256 floats = 2 MB (transposed)
  float* xg = ws + SEQ * BATCH * G4;       // 4096 floats
  int*  flg = (int*)(xg + BATCH * NN * 8); // 260 flag ints (0xAA-poison = not ready)
  float* out = (float*)d_out;

  hipLaunchKernelGGL(fused_all, dim3(132), dim3(256), 0, stream,
                     x, adj, emb_w, emb_b, g1W, g1a, g2W, g2a,
                     Wih0, Whh0, bih0, bhh0, Wih1, Whh1, bih1, bhh1,
                     dw1, db1, dw2, db2, rw1, rb1, rw2, rb2,
                     vw1, vb1, vw2, vb2,
                     X0, xg, flg, out);
}

// Round 6
// 400.612 us; speedup vs baseline: 1.1117x; 1.0305x over previous
//
#include <hip/hip_runtime.h>

#define SEQ   512
#define BATCH 4
#define NN    128
#define HID   64
#define G4    256   // 4*HID gates per layer
#define MAGIC 0x13579BDF

typedef _Float16 half2v __attribute__((ext_vector_type(2)));

// Fast activations: v_exp_f32 + v_rcp_f32 (abs err ~1e-6, threshold is 1e-3)
__device__ __forceinline__ float frcp(float x)  { return __builtin_amdgcn_rcpf(x); }
__device__ __forceinline__ float fsigm(float x) { return frcp(1.f + __expf(-x)); }
__device__ __forceinline__ float ftanh(float x) { return 1.f - 2.f * frcp(1.f + __expf(2.f * x)); }
__device__ __forceinline__ float lrelu(float x) { return x > 0.f ? x : 0.2f * x; }
__device__ __forceinline__ float dot4f(float4 w, float4 h) {
  return fmaf(w.x, h.x, fmaf(w.y, h.y, fmaf(w.z, h.z, w.w * h.w)));
}
__device__ __forceinline__ void pin4(float4& v) {
  asm volatile("" : "+v"(v.x), "+v"(v.y), "+v"(v.z), "+v"(v.w));
}
__device__ __forceinline__ half2v u2h(unsigned u) {
  return __builtin_bit_cast(half2v, u);
}
// Pack two f32 -> f16x2 (RTZ packed cvt).
__device__ __forceinline__ half2v pk16(float lo, float hi) {
  return __builtin_bit_cast(half2v, __builtin_amdgcn_cvt_pkrtz(lo, hi));
}
// v_dot2_f32_f16: 2 f16 MACs, f32 accumulate (exact products, f32 sum).
__device__ __forceinline__ float fdot2(half2v a, half2v b, float c) {
#if __has_builtin(__builtin_amdgcn_fdot2)
  return __builtin_amdgcn_fdot2(a, b, c, false);
#else
  float d = c;
  asm("v_dot2_f32_f16 %0, %1, %2, %0" : "+v"(d) : "v"(a), "v"(b));
  return d;
#endif
}
// 16-elem f16 dot: 8 chained v_dot2 (w = 8 half2, h = two uint4 of packed f16).
__device__ __forceinline__ float dot8h(const half2v* w, const uint4& a,
                                       const uint4& b, float acc) {
  acc = fdot2(w[0], u2h(a.x), acc);
  acc = fdot2(w[1], u2h(a.y), acc);
  acc = fdot2(w[2], u2h(a.z), acc);
  acc = fdot2(w[3], u2h(a.w), acc);
  acc = fdot2(w[4], u2h(b.x), acc);
  acc = fdot2(w[5], u2h(b.y), acc);
  acc = fdot2(w[6], u2h(b.z), acc);
  acc = fdot2(w[7], u2h(b.w), acc);
  return acc;
}
// Quad_perm {1,0,3,2}: even lane gets odd neighbor's value (self-inverse).
__device__ __forceinline__ float nbr1(float x) {
  return __int_as_float(__builtin_amdgcn_update_dpp(
      0, __float_as_int(x), 0xB1, 0xF, 0xF, true));
}

// LDS-only barrier: s_waitcnt lgkmcnt(0) + s_barrier, NO vmcnt(0) drain.
#define BAR_LDS() asm volatile("s_waitcnt lgkmcnt(0)\n\ts_barrier" ::: "memory")

// ---------------------------------------------------------------------------
// fused_all: ONE kernel, 132 blocks x 256 threads.
//   blocks 0-3   : LSTM scan + heads, gated on banded X0 flags.
//   blocks 4-131 : X0 producer, band-interleaved; blocks 4-7 then GAT.
// R17: consumer restructured as a WAVE-SPECIALIZED PIPELINE. R16 proved the
//   step is latency-bound on one thread's serial chain (issue ~400cy vs
//   measured 1484cy/step). Now each matvec gets its own wave with full
//   64-dim dots per lane (no qsum):
//     wave0: h0[k]   = gates(Whh0*h0[k-1] + X0[k])     (self-loop via hb0)
//     wave1: SB[k]   = Wih1*h0[k-1] + b1               (reads hb0, writes SBb)
//     wave2: h1[k-2] = gates(SB[k-1] + Whh1*h1[k-3])   (self-loop via hb1)
//     wave3: barrier-only idler (keeps producer/heads 256-thread layout).
//   One barrier per interval; steady state = max(wave chains), pipelined.
//   h vectors packed f16x2 (32 dwords), broadcast-read 8x ds_read_b128.
// ---------------------------------------------------------------------------
__global__ __attribute__((amdgpu_flat_work_group_size(256, 256),
                          amdgpu_waves_per_eu(1, 4)))
void fused_all(
    const float* __restrict__ x, const int* __restrict__ adj,
    const float* __restrict__ emb_w, const float* __restrict__ emb_b,
    const float* __restrict__ W1, const float* __restrict__ a1,
    const float* __restrict__ W2, const float* __restrict__ a2,
    const float* __restrict__ Wih0, const float* __restrict__ Whh0,
    const float* __restrict__ bih0, const float* __restrict__ bhh0,
    const float* __restrict__ Wih1, const float* __restrict__ Whh1,
    const float* __restrict__ bih1, const float* __restrict__ bhh1,
    const float* __restrict__ dw1, const float* __restrict__ db1,
    const float* __restrict__ dw2, const float* __restrict__ db2,
    const float* __restrict__ rw1, const float* __restrict__ rb1,
    const float* __restrict__ rw2, const float* __restrict__ rb2,
    const float* __restrict__ vw1, const float* __restrict__ vb1,
    const float* __restrict__ vw2, const float* __restrict__ vb2,
    float* __restrict__ X0T, float* __restrict__ xg,
    int* __restrict__ flags, float* __restrict__ out)
{
  const int bid = blockIdx.x;
  const int tid = threadIdx.x;

  if (bid >= 4) {
    // =================== PRODUCER: band-interleaved X0 ===================
    const int c = bid - 4;
    __shared__ __align__(16) float xls[NN];
    {
      const int g = tid;                       // one gate per thread
      float4 w4[32];
      {
        const float4* wp = reinterpret_cast<const float4*>(Wih0 + g * NN);
#pragma unroll
        for (int i = 0; i < 32; ++i) w4[i] = wp[i];
#pragma unroll
        for (int i = 0; i < 32; ++i) pin4(w4[i]);
      }
      const float bsum = bih0[g] + bhh0[g];
      for (int phase = 0; phase < 4; ++phase) {
        const int T = c + 128 * phase;
        for (int bb = 0; bb < BATCH; ++bb) {
          if (tid < NN) xls[tid] = x[(bb * SEQ + T) * NN + tid];
          __syncthreads();
          {
            const float4* hp = reinterpret_cast<const float4*>(xls);
            float p0 = 0.f, p1 = 0.f, p2 = 0.f, p3 = 0.f;
#pragma unroll
            for (int k = 0; k < 32; k += 4) {
              p0 += dot4f(w4[k],     hp[k]);
              p1 += dot4f(w4[k + 1], hp[k + 1]);
              p2 += dot4f(w4[k + 2], hp[k + 2]);
              p3 += dot4f(w4[k + 3], hp[k + 3]);
            }
            X0T[(4 * T + bb) * G4 + (g & 63) * 4 + (g >> 6)] =
                ((p0 + p1) + (p2 + p3)) + bsum;
          }
          __syncthreads();   // drains this block's X0 stores before flag release
        }
        if (tid == 0 && phase == 0)
          __hip_atomic_store(&flags[c], MAGIC, __ATOMIC_RELEASE,
                             __HIP_MEMORY_SCOPE_AGENT);
        if (tid == 0 && phase == 3)
          __hip_atomic_store(&flags[128 + c], MAGIC, __ATOMIC_RELEASE,
                             __HIP_MEMORY_SCOPE_AGENT);
      }
    }
    if (bid >= 8) return;

    // =================== GAT (blocks 4-7, batch b) ===================
    const int b = bid - 4;
    __shared__ float adjm[NN * 129];
    __shared__ __align__(16) float gxls[NN];
    __shared__ float u[16], v[16];
    __shared__ float Wh2[NN][9];
    __shared__ float f1b[NN], f2b[NN];
    __shared__ float p[NN];

    for (int idx = tid; idx < NN * NN; idx += 256)
      adjm[(idx >> 7) * 129 + (idx & 127)] = (adj[idx] > 0) ? 1.f : 0.f;
    if (tid < NN) gxls[tid] = x[(b * SEQ + (SEQ - 1)) * NN + tid];
    if (tid < 16) {
      float uu = 0.f, vv = 0.f;
      for (int fp = 0; fp < 16; ++fp) {
        uu += emb_w[fp] * W1[fp * 16 + tid];
        vv += emb_b[fp] * W1[fp * 16 + tid];
      }
      u[tid] = uu; v[tid] = vv;
    }
    __syncthreads();
    float s1 = 0.f, t1 = 0.f, s2 = 0.f, t2 = 0.f;
    for (int f = 0; f < 16; ++f) {
      s1 += u[f] * a1[f];      t1 += v[f] * a1[f];
      s2 += u[f] * a1[16 + f]; t2 += v[f] * a1[16 + f];
    }
    if (tid < NN) {
      const int i = tid;
      const float f1i = gxls[i] * s1 + t1;
      float m = -1e30f;
      for (int j = 0; j < NN; ++j)
        if (adjm[i * 129 + j] != 0.f)
          m = fmaxf(m, lrelu(f1i + gxls[j] * s2 + t2));
      float ssum = 0.f, ps = 0.f;
      for (int j = 0; j < NN; ++j)
        if (adjm[i * 129 + j] != 0.f) {
          const float wgt = __expf(lrelu(f1i + gxls[j] * s2 + t2) - m);
          ssum += wgt; ps += wgt * gxls[j];
        }
      p[i] = ps / ssum;
    }
    __syncthreads();
    if (tid < NN) {
      const int i = tid;
      float xg1[16];
#pragma unroll
      for (int f = 0; f < 16; ++f) {
        const float ov = p[i] * u[f] + v[f];
        xg1[f] = ov > 0.f ? ov : expm1f(ov);
      }
      float wrow[8];
#pragma unroll
      for (int f2 = 0; f2 < 8; ++f2) wrow[f2] = 0.f;
#pragma unroll
      for (int f = 0; f < 16; ++f) {
        const float xv = xg1[f];
#pragma unroll
        for (int f2 = 0; f2 < 8; ++f2) wrow[f2] += xv * W2[f * 8 + f2];
      }
      float fb1 = 0.f, fb2 = 0.f;
#pragma unroll
      for (int f2 = 0; f2 < 8; ++f2) {
        Wh2[i][f2] = wrow[f2];
        fb1 += wrow[f2] * a2[f2];
        fb2 += wrow[f2] * a2[8 + f2];
      }
      f1b[i] = fb1; f2b[i] = fb2;
    }
    __syncthreads();
    if (tid < NN) {
      const int i = tid;
      const float fi = f1b[i];
      float m = -1e30f;
      for (int j = 0; j < NN; ++j)
        if (adjm[i * 129 + j] != 0.f)
          m = fmaxf(m, lrelu(fi + f2b[j]));
      float ssum = 0.f;
      float o[8];
#pragma unroll
      for (int f2 = 0; f2 < 8; ++f2) o[f2] = 0.f;
      for (int j = 0; j < NN; ++j)
        if (adjm[i * 129 + j] != 0.f) {
          const float wgt = __expf(lrelu(fi + f2b[j]) - m);
          ssum += wgt;
#pragma unroll
          for (int f2 = 0; f2 < 8; ++f2) o[f2] += wgt * Wh2[j][f2];
        }
      const float inv = 1.f / ssum;
#pragma unroll
      for (int f2 = 0; f2 < 8; ++f2)
        xg[b * (NN * 8) + i * 8 + f2] = o[f2] * inv;
    }
    __syncthreads();
    if (tid == 0)
      __hip_atomic_store(&flags[256 + b], MAGIC, __ATOMIC_RELEASE,
                         __HIP_MEMORY_SCOPE_AGENT);
    return;
  }

  // =================== CONSUMER: wave-specialized LSTM pipeline ============
  const int b   = bid;
  const int t   = tid;
  const int wid = t >> 6;           // wave role 0..3
  const int l   = t & 63;           // lane = unit

  // h vectors packed f16x2: 64 f16 = 32 dwords per buffer. Dbuf by parity.
  __shared__ __align__(16) unsigned hb0[2][32];
  __shared__ __align__(16) unsigned hb1[2][32];
  __shared__ __align__(16) float SBb[2][G4];   // [parity][unit*4+gate]
  __shared__ float cbuf[1088];
  __shared__ float hidc[96];

  // Full-row f16 weights: 4 gates x 64 dims = 128 dwords (static indexing).
  const float* Wsrc = (wid == 0) ? Whh0 : (wid == 1) ? Wih1 : Whh1;
  half2v w[4][32];
  if (wid < 3) {
#pragma unroll
    for (int j = 0; j < 4; ++j) {
      const float* wr = Wsrc + (l + 64 * j) * HID;
#pragma unroll
      for (int c = 0; c < 16; ++c) {
        const float4 wv = *reinterpret_cast<const float4*>(wr + 4 * c);
        w[j][2 * c]     = half2v{(_Float16)wv.x, (_Float16)wv.y};
        w[j][2 * c + 1] = half2v{(_Float16)wv.z, (_Float16)wv.w};
      }
    }
  }
  // layer-1 bias, folded into wave1's dot accumulators.
  float4 b1v = make_float4(0.f, 0.f, 0.f, 0.f);
  if (wid == 1) {
    b1v.x = bih1[l]       + bhh1[l];
    b1v.y = bih1[l + 64]  + bhh1[l + 64];
    b1v.z = bih1[l + 128] + bhh1[l + 128];
    b1v.w = bih1[l + 192] + bhh1[l + 192];
  }

  if (t < 64) reinterpret_cast<unsigned*>(hb0)[t] = 0u;   // both parities
  if (t < 64) reinterpret_cast<unsigned*>(hb1)[t] = 0u;
  float cst0 = 0.f, cst1 = 0.f;
  const float* X0b = X0T + b * G4 + l * 4;

  // Initial frontier: flags[0..31] (32-wide parallel acquire-RMW poll).
  int c_ok;
  {
    if (t < 32) {
      while (__hip_atomic_fetch_add(&flags[t], 0, __ATOMIC_ACQUIRE,
                                    __HIP_MEMORY_SCOPE_AGENT) != MAGIC) {}
    }
    __syncthreads();   // also makes hb0/hb1 zeroing visible
    c_ok = 31;
  }

  // 2-deep X0 prefetch (wave0 consumes; ~1400cy lead at predicted step time).
  float4 xa0 = make_float4(0.f, 0.f, 0.f, 0.f), xa1 = xa0;
  if (wid == 0) {
    xa0 = *reinterpret_cast<const float4*>(X0b + 0 * (BATCH * G4));
    xa1 = *reinterpret_cast<const float4*>(X0b + 1 * (BATCH * G4));
  }

#define LOAD_H8(SRC, RB)                                                       \
  const uint4* hp_ = reinterpret_cast<const uint4*>(&SRC[RB][0]);              \
  const uint4 v0 = hp_[0], v1 = hp_[1], v2 = hp_[2], v3 = hp_[3];              \
  const uint4 v4 = hp_[4], v5 = hp_[5], v6 = hp_[6], v7 = hp_[7]

#define DOT64(G, ACC0)                                                         \
  dot8h(&w[G][24], v6, v7,                                                     \
  dot8h(&w[G][16], v4, v5,                                                     \
  dot8h(&w[G][8],  v2, v3,                                                     \
  dot8h(&w[G][0],  v0, v1, (ACC0)))))

#define PACK_W(DST, WB, HV)                                                    \
  do {                                                                         \
    const float nb_ = nbr1(HV);                                                \
    if ((l & 1) == 0)                                                          \
      DST[WB][l >> 1] = __builtin_bit_cast(unsigned, pk16((HV), nb_));         \
  } while (0)

// Interval K: wave0 makes h0[K]; wave1 makes SB[K]=Wih1*h0[K-1]+b1;
// wave2 makes h1[K-2]=gates(SB[K-1]+Whh1*h1[K-3]). One barrier per interval.
#define INT_STEP(K, RB, WB, XV)                                                \
  do {                                                                         \
    if (wid == 0) {                                                            \
      if ((K) < SEQ) {                                                         \
        LOAD_H8(hb0, RB);                                                      \
        const float A0 = DOT64(0, 0.f);                                        \
        const float A1 = DOT64(1, 0.f);                                        \
        const float A2 = DOT64(2, 0.f);                                        \
        const float A3 = DOT64(3, 0.f);                                        \
        const float gi = fsigm(A0 + (XV).x);                                   \
        const float gf = fsigm(A1 + (XV).y);                                   \
        const float gg = ftanh(A2 + (XV).z);                                   \
        const float go = fsigm(A3 + (XV).w);                                   \
        cst0 = fmaf(gf, cst0, gi * gg);                                        \
        const float hv = go * ftanh(cst0);                                     \
        PACK_W(hb0, WB, hv);                                                   \
      }                                                                        \
    } else if (wid == 1) {                                                     \
      if ((K) >= 1 && (K) <= SEQ) {                                            \
        LOAD_H8(hb0, RB);                                                      \
        const float B0 = DOT64(0, b1v.x);                                      \
        const float B1 = DOT64(1, b1v.y);                                      \
        const float B2 = DOT64(2, b1v.z);                                      \
        const float B3 = DOT64(3, b1v.w);                                      \
        *reinterpret_cast<float4*>(&SBb[WB][l * 4]) =                          \
            make_float4(B0, B1, B2, B3);                                       \
      }                                                                        \
    } else if (wid == 2) {                                                     \
      if ((K) >= 2) {                                                          \
        LOAD_H8(hb1, RB);                                                      \
        const float C0 = DOT64(0, 0.f);                                        \
        const float C1 = DOT64(1, 0.f);                                        \
        const float C2 = DOT64(2, 0.f);                                        \
        const float C3 = DOT64(3, 0.f);                                        \
        const float4 sb = *reinterpret_cast<const float4*>(&SBb[RB][l * 4]);   \
        const float gi = fsigm(C0 + sb.x);                                     \
        const float gf = fsigm(C1 + sb.y);                                     \
        const float gg = ftanh(C2 + sb.z);                                     \
        const float go = fsigm(C3 + sb.w);                                     \
        cst1 = fmaf(gf, cst1, gi * gg);                                        \
        const float hv = go * ftanh(cst1);                                     \
        PACK_W(hb1, WB, hv);                                                   \
      }                                                                        \
    }                                                                          \
    BAR_LDS();                                                                 \
  } while (0)

  for (int k = 0; k < SEQ + 2; k += 2) {   // intervals K = k, k+1 (514 total)
    // Frontier advance: 32-wide batch; wave0 consumes X0[k..k+3].
    if (k + 8 > c_ok && c_ok < 255) {
      const int base = c_ok + 1;
      if (t < 32 && base + t <= 255) {
        while (__hip_atomic_fetch_add(&flags[base + t], 0, __ATOMIC_ACQUIRE,
                                      __HIP_MEMORY_SCOPE_AGENT) != MAGIC) {}
      }
      __syncthreads();
      c_ok = (base + 31 < 255) ? base + 31 : 255;
    }
    if (wid < 3) {
#pragma unroll
      for (int j = 0; j < 4; ++j) {
        half2v* wp = &w[j][0];
        asm volatile("" : "+v"(wp[0]), "+v"(wp[1]), "+v"(wp[2]), "+v"(wp[3]),
                          "+v"(wp[4]), "+v"(wp[5]), "+v"(wp[6]), "+v"(wp[7]));
        asm volatile("" : "+v"(wp[8]), "+v"(wp[9]), "+v"(wp[10]), "+v"(wp[11]),
                          "+v"(wp[12]), "+v"(wp[13]), "+v"(wp[14]), "+v"(wp[15]));
        asm volatile("" : "+v"(wp[16]), "+v"(wp[17]), "+v"(wp[18]), "+v"(wp[19]),
                          "+v"(wp[20]), "+v"(wp[21]), "+v"(wp[22]), "+v"(wp[23]));
        asm volatile("" : "+v"(wp[24]), "+v"(wp[25]), "+v"(wp[26]), "+v"(wp[27]),
                          "+v"(wp[28]), "+v"(wp[29]), "+v"(wp[30]), "+v"(wp[31]));
      }
    }
    // Issue next 2 X0 loads; in flight across the BAR_LDS barriers.
    float4 xb0 = xa0, xb1 = xa1;
    if (wid == 0 && k + 2 < SEQ) {
      xb0 = *reinterpret_cast<const float4*>(X0b + (k + 2) * (BATCH * G4));
      xb1 = *reinterpret_cast<const float4*>(X0b + (k + 3) * (BATCH * G4));
    }
    INT_STEP(k,     1, 0, xa0);
    INT_STEP(k + 1, 0, 1, xa1);
    xa0 = xb0; xa1 = xb1;
  }
#undef INT_STEP
#undef PACK_W
#undef DOT64
#undef LOAD_H8
  // h1[511] written at interval 513 (parity 1) -> hb1[1].

  // wait for this batch's GAT result
  if (t == 0) {
    while (__hip_atomic_fetch_add(&flags[256 + b], 0, __ATOMIC_ACQUIRE,
                                  __HIP_MEMORY_SCOPE_AGENT) != MAGIC) {}
  }
  __syncthreads();

  // ---------------- fused heads: c = [h1(64) | xg_b(1024)] ----------------
  if (t < 64) {
    const _Float16* hh = reinterpret_cast<const _Float16*>(&hb1[1][0]);
    cbuf[t] = (float)hh[t];
  }
  for (int k = t; k < 1024; k += 256) cbuf[64 + k] = xg[b * 1024 + k];
  __syncthreads();
  if (t < 96) {
    const int head = t >> 5, h = t & 31;
    const float* w1 = (head == 0) ? dw1 : (head == 1) ? rw1 : vw1;
    const float* b1 = (head == 0) ? db1 : (head == 1) ? rb1 : vb1;
    float a0 = 0.f, a1v = 0.f, a2v = 0.f, a3v = 0.f;
    for (int k = 0; k < 1088; k += 4) {
      a0  = fmaf(cbuf[k],     w1[k * 32 + h],       a0);
      a1v = fmaf(cbuf[k + 1], w1[(k + 1) * 32 + h], a1v);
      a2v = fmaf(cbuf[k + 2], w1[(k + 2) * 32 + h], a2v);
      a3v = fmaf(cbuf[k + 3], w1[(k + 3) * 32 + h], a3v);
    }
    hidc[head * 32 + h] = fmaxf(b1[h] + ((a0 + a1v) + (a2v + a3v)), 0.f);
  }
  __syncthreads();
  if (t < 4) {
    const int head2 = (t < 2) ? t : 2;
    const int o = (t < 2) ? 0 : (t - 2);
    const int odim = (t < 2) ? 1 : 2;
    const float* w2  = (head2 == 0) ? dw2 : (head2 == 1) ? rw2 : vw2;
    const float* b2p = (head2 == 0) ? db2 : (head2 == 1) ? rb2 : vb2;
    float acc = b2p[o];
    for (int hh = 0; hh < 32; ++hh)
      acc = fmaf(hidc[head2 * 32 + hh], w2[hh * odim + o], acc);
    const int off = (t == 0) ? b : (t == 1) ? (4 + b) : (8 + 2 * b + o);
    out[off] = acc;   // [dir(4) | ret(4) | vol(4x2)] flat
  }
}

// ---------------------------------------------------------------------------
extern "C" void kernel_launch(void* const* d_in, const int* in_sizes, int n_in,
                              void* d_out, int out_size, void* d_ws, size_t ws_size,
                              hipStream_t stream) {
  const float* x     = (const float*)d_in[0];
  const int*   adj   = (const int*)  d_in[1];
  const float* emb_w = (const float*)d_in[2];
  const float* emb_b = (const float*)d_in[3];
  const float* g1W   = (const float*)d_in[4];
  const float* g1a   = (const float*)d_in[5];
  const float* g2W   = (const float*)d_in[6];
  const float* g2a   = (const float*)d_in[7];
  const float* Wih0  = (const float*)d_in[8];
  const float* Whh0  = (const float*)d_in[9];
  const float* bih0  = (const float*)d_in[10];
  const float* bhh0  = (const float*)d_in[11];
  const float* Wih1  = (const float*)d_in[12];
  const float* Whh1  = (const float*)d_in[13];
  const float* bih1  = (const float*)d_in[14];
  const float* bhh1  = (const float*)d_in[15];
  const float* dw1 = (const float*)d_in[16]; const float* db1 = (const float*)d_in[17];
  const float* dw2 = (const float*)d_in[18]; const float* db2 = (const float*)d_in[19];
  const float* rw1 = (const float*)d_in[20]; const float* rb1 = (const float*)d_in[21];
  const float* rw2 = (const float*)d_in[22]; const float* rb2 = (const float*)d_in[23];
  const float* vw1 = (const float*)d_in[24]; const float* vb1 = (const float*)d_in[25];
  const float* vw2 = (const float*)d_in[26]; const float* vb2 = (const float*)d_in[27];

  float* ws = (float*)d_ws;
  float* X0 = ws;                          // SEQ*BATCH*256 floats = 2 MB (transposed)
  float* xg = ws + SEQ * BATCH * G4;       // 4096 floats
  int*  flg = (int*)(xg + BATCH * NN * 8); // 260 flag ints (0xAA-poison = not ready)
  float* out = (float*)d_out;

  hipLaunchKernelGGL(fused_all, dim3(132), dim3(256), 0, stream,
                     x, adj, emb_w, emb_b, g1W, g1a, g2W, g2a,
                     Wih0, Whh0, bih0, bhh0, Wih1, Whh1, bih1, bhh1,
                     dw1, db1, dw2, db2, rw1, rb1, rw2, rb2,
                     vw1, vb1, vw2, vb2,
                     X0, xg, flg, out);
}

// Round 7
// 390.008 us; speedup vs baseline: 1.1419x; 1.0272x over previous
//
#include <hip/hip_runtime.h>

#define SEQ   512
#define BATCH 4
#define NN    128
#define HID   64
#define G4    256   // 4*HID gates per layer
#define MAGIC 0x13579BDF

typedef _Float16 half2v __attribute__((ext_vector_type(2)));

// Fast activations: v_exp_f32 + v_rcp_f32 (abs err ~1e-6, threshold is 1e-3)
__device__ __forceinline__ float frcp(float x)  { return __builtin_amdgcn_rcpf(x); }
__device__ __forceinline__ float fsigm(float x) { return frcp(1.f + __expf(-x)); }
__device__ __forceinline__ float ftanh(float x) { return 1.f - 2.f * frcp(1.f + __expf(2.f * x)); }
__device__ __forceinline__ float lrelu(float x) { return x > 0.f ? x : 0.2f * x; }
__device__ __forceinline__ float dot4f(float4 w, float4 h) {
  return fmaf(w.x, h.x, fmaf(w.y, h.y, fmaf(w.z, h.z, w.w * h.w)));
}
__device__ __forceinline__ void pin4(float4& v) {
  asm volatile("" : "+v"(v.x), "+v"(v.y), "+v"(v.z), "+v"(v.w));
}
__device__ __forceinline__ half2v u2h(unsigned u) {
  return __builtin_bit_cast(half2v, u);
}
// v_dot2_f32_f16: 2 f16 MACs, f32 accumulate (exact products, f32 sum).
__device__ __forceinline__ float fdot2(half2v a, half2v b, float c) {
#if __has_builtin(__builtin_amdgcn_fdot2)
  return __builtin_amdgcn_fdot2(a, b, c, false);
#else
  float d = c;
  asm("v_dot2_f32_f16 %0, %1, %2, %0" : "+v"(d) : "v"(a), "v"(b));
  return d;
#endif
}
// 16-elem f16 dot: 8 chained v_dot2 (w = 8 half2, h = two uint4 of packed f16).
__device__ __forceinline__ float dot8h(const half2v* w, const uint4& a,
                                       const uint4& b, float acc) {
  acc = fdot2(w[0], u2h(a.x), acc);
  acc = fdot2(w[1], u2h(a.y), acc);
  acc = fdot2(w[2], u2h(a.z), acc);
  acc = fdot2(w[3], u2h(a.w), acc);
  acc = fdot2(w[4], u2h(b.x), acc);
  acc = fdot2(w[5], u2h(b.y), acc);
  acc = fdot2(w[6], u2h(b.z), acc);
  acc = fdot2(w[7], u2h(b.w), acc);
  return acc;
}

// LDS-only barrier: s_waitcnt lgkmcnt(0) + s_barrier, NO vmcnt(0) drain.
#define BAR_LDS() asm volatile("s_waitcnt lgkmcnt(0)\n\ts_barrier" ::: "memory")

// ---------------------------------------------------------------------------
// fused_all: ONE kernel, 132 blocks x 256 threads.
//   blocks 0-3   : LSTM scan + heads, gated on banded X0 flags.
//   blocks 4-131 : X0 producer, band-interleaved; blocks 4-7 then GAT.
// R18: wave-specialized pipeline with BARRIER EVERY 2 INTERVALS (was 1).
//   4-deep h0/h1/SB buffers; consumers lag so every cross-wave read is >=1
//   epoch (2 intervals) behind its writer; intra-wave self-loops (wave0 h0,
//   wave2 h1) rely on per-wave in-order LDS, no barrier needed.
//     wave0 @K: h0[K]   = gates(Whh0*h0[K-1] + X0[K])      buf (K-1)&3 -> K&3
//     wave1 @K: SB[K-2] = Wih1*h0[K-2] + b1                 (prev epoch read)
//     wave2 @K: h1[K-4] = gates(SB[K-4] + Whh1*h1[K-5])     (prev epoch read)
//   516 intervals, 258 barriers (was 514). X0 folded into dot-acc init; h
//   pack via per-lane ds_write_b16 (DPP pair-pack removed from chain).
// ---------------------------------------------------------------------------
__global__ __attribute__((amdgpu_flat_work_group_size(256, 256),
                          amdgpu_waves_per_eu(1, 4)))
void fused_all(
    const float* __restrict__ x, const int* __restrict__ adj,
    const float* __restrict__ emb_w, const float* __restrict__ emb_b,
    const float* __restrict__ W1, const float* __restrict__ a1,
    const float* __restrict__ W2, const float* __restrict__ a2,
    const float* __restrict__ Wih0, const float* __restrict__ Whh0,
    const float* __restrict__ bih0, const float* __restrict__ bhh0,
    const float* __restrict__ Wih1, const float* __restrict__ Whh1,
    const float* __restrict__ bih1, const float* __restrict__ bhh1,
    const float* __restrict__ dw1, const float* __restrict__ db1,
    const float* __restrict__ dw2, const float* __restrict__ db2,
    const float* __restrict__ rw1, const float* __restrict__ rb1,
    const float* __restrict__ rw2, const float* __restrict__ rb2,
    const float* __restrict__ vw1, const float* __restrict__ vb1,
    const float* __restrict__ vw2, const float* __restrict__ vb2,
    float* __restrict__ X0T, float* __restrict__ xg,
    int* __restrict__ flags, float* __restrict__ out)
{
  const int bid = blockIdx.x;
  const int tid = threadIdx.x;

  if (bid >= 4) {
    // =================== PRODUCER: band-interleaved X0 ===================
    const int c = bid - 4;
    __shared__ __align__(16) float xls[NN];
    {
      const int g = tid;                       // one gate per thread
      float4 w4[32];
      {
        const float4* wp = reinterpret_cast<const float4*>(Wih0 + g * NN);
#pragma unroll
        for (int i = 0; i < 32; ++i) w4[i] = wp[i];
#pragma unroll
        for (int i = 0; i < 32; ++i) pin4(w4[i]);
      }
      const float bsum = bih0[g] + bhh0[g];
      for (int phase = 0; phase < 4; ++phase) {
        const int T = c + 128 * phase;
        for (int bb = 0; bb < BATCH; ++bb) {
          if (tid < NN) xls[tid] = x[(bb * SEQ + T) * NN + tid];
          __syncthreads();
          {
            const float4* hp = reinterpret_cast<const float4*>(xls);
            float p0 = 0.f, p1 = 0.f, p2 = 0.f, p3 = 0.f;
#pragma unroll
            for (int k = 0; k < 32; k += 4) {
              p0 += dot4f(w4[k],     hp[k]);
              p1 += dot4f(w4[k + 1], hp[k + 1]);
              p2 += dot4f(w4[k + 2], hp[k + 2]);
              p3 += dot4f(w4[k + 3], hp[k + 3]);
            }
            X0T[(4 * T + bb) * G4 + (g & 63) * 4 + (g >> 6)] =
                ((p0 + p1) + (p2 + p3)) + bsum;
          }
          __syncthreads();   // drains this block's X0 stores before flag release
        }
        if (tid == 0 && phase == 0)
          __hip_atomic_store(&flags[c], MAGIC, __ATOMIC_RELEASE,
                             __HIP_MEMORY_SCOPE_AGENT);
        if (tid == 0 && phase == 3)
          __hip_atomic_store(&flags[128 + c], MAGIC, __ATOMIC_RELEASE,
                             __HIP_MEMORY_SCOPE_AGENT);
      }
    }
    if (bid >= 8) return;

    // =================== GAT (blocks 4-7, batch b) ===================
    const int b = bid - 4;
    __shared__ float adjm[NN * 129];
    __shared__ __align__(16) float gxls[NN];
    __shared__ float u[16], v[16];
    __shared__ float Wh2[NN][9];
    __shared__ float f1b[NN], f2b[NN];
    __shared__ float p[NN];

    for (int idx = tid; idx < NN * NN; idx += 256)
      adjm[(idx >> 7) * 129 + (idx & 127)] = (adj[idx] > 0) ? 1.f : 0.f;
    if (tid < NN) gxls[tid] = x[(b * SEQ + (SEQ - 1)) * NN + tid];
    if (tid < 16) {
      float uu = 0.f, vv = 0.f;
      for (int fp = 0; fp < 16; ++fp) {
        uu += emb_w[fp] * W1[fp * 16 + tid];
        vv += emb_b[fp] * W1[fp * 16 + tid];
      }
      u[tid] = uu; v[tid] = vv;
    }
    __syncthreads();
    float s1 = 0.f, t1 = 0.f, s2 = 0.f, t2 = 0.f;
    for (int f = 0; f < 16; ++f) {
      s1 += u[f] * a1[f];      t1 += v[f] * a1[f];
      s2 += u[f] * a1[16 + f]; t2 += v[f] * a1[16 + f];
    }
    if (tid < NN) {
      const int i = tid;
      const float f1i = gxls[i] * s1 + t1;
      float m = -1e30f;
      for (int j = 0; j < NN; ++j)
        if (adjm[i * 129 + j] != 0.f)
          m = fmaxf(m, lrelu(f1i + gxls[j] * s2 + t2));
      float ssum = 0.f, ps = 0.f;
      for (int j = 0; j < NN; ++j)
        if (adjm[i * 129 + j] != 0.f) {
          const float wgt = __expf(lrelu(f1i + gxls[j] * s2 + t2) - m);
          ssum += wgt; ps += wgt * gxls[j];
        }
      p[i] = ps / ssum;
    }
    __syncthreads();
    if (tid < NN) {
      const int i = tid;
      float xg1[16];
#pragma unroll
      for (int f = 0; f < 16; ++f) {
        const float ov = p[i] * u[f] + v[f];
        xg1[f] = ov > 0.f ? ov : expm1f(ov);
      }
      float wrow[8];
#pragma unroll
      for (int f2 = 0; f2 < 8; ++f2) wrow[f2] = 0.f;
#pragma unroll
      for (int f = 0; f < 16; ++f) {
        const float xv = xg1[f];
#pragma unroll
        for (int f2 = 0; f2 < 8; ++f2) wrow[f2] += xv * W2[f * 8 + f2];
      }
      float fb1 = 0.f, fb2 = 0.f;
#pragma unroll
      for (int f2 = 0; f2 < 8; ++f2) {
        Wh2[i][f2] = wrow[f2];
        fb1 += wrow[f2] * a2[f2];
        fb2 += wrow[f2] * a2[8 + f2];
      }
      f1b[i] = fb1; f2b[i] = fb2;
    }
    __syncthreads();
    if (tid < NN) {
      const int i = tid;
      const float fi = f1b[i];
      float m = -1e30f;
      for (int j = 0; j < NN; ++j)
        if (adjm[i * 129 + j] != 0.f)
          m = fmaxf(m, lrelu(fi + f2b[j]));
      float ssum = 0.f;
      float o[8];
#pragma unroll
      for (int f2 = 0; f2 < 8; ++f2) o[f2] = 0.f;
      for (int j = 0; j < NN; ++j)
        if (adjm[i * 129 + j] != 0.f) {
          const float wgt = __expf(lrelu(fi + f2b[j]) - m);
          ssum += wgt;
#pragma unroll
          for (int f2 = 0; f2 < 8; ++f2) o[f2] += wgt * Wh2[j][f2];
        }
      const float inv = 1.f / ssum;
#pragma unroll
      for (int f2 = 0; f2 < 8; ++f2)
        xg[b * (NN * 8) + i * 8 + f2] = o[f2] * inv;
    }
    __syncthreads();
    if (tid == 0)
      __hip_atomic_store(&flags[256 + b], MAGIC, __ATOMIC_RELEASE,
                         __HIP_MEMORY_SCOPE_AGENT);
    return;
  }

  // =================== CONSUMER: wave-specialized LSTM pipeline ============
  const int b   = bid;
  const int t   = tid;
  const int wid = t >> 6;           // wave role 0..3 (wave3 idles at barriers)
  const int l   = t & 63;           // lane = unit

  // 4-deep packed-f16 h buffers (32 dwords each) + 4-deep SB float4 buffer.
  __shared__ __align__(16) unsigned hb0[4][32];
  __shared__ __align__(16) unsigned hb1[4][32];
  __shared__ __align__(16) float4 SBb[4][64];
  __shared__ float cbuf[1088];
  __shared__ float hidc[96];

  // Full-row f16 weights: 4 gates x 64 dims = 128 dwords (static indexing).
  const float* Wsrc = (wid == 0) ? Whh0 : (wid == 1) ? Wih1 : Whh1;
  half2v w[4][32];
  if (wid < 3) {
#pragma unroll
    for (int j = 0; j < 4; ++j) {
      const float* wr = Wsrc + (l + 64 * j) * HID;
#pragma unroll
      for (int c = 0; c < 16; ++c) {
        const float4 wv = *reinterpret_cast<const float4*>(wr + 4 * c);
        w[j][2 * c]     = half2v{(_Float16)wv.x, (_Float16)wv.y};
        w[j][2 * c + 1] = half2v{(_Float16)wv.z, (_Float16)wv.w};
      }
    }
  }
  // layer-1 bias, folded into wave1's dot accumulators.
  float4 b1v = make_float4(0.f, 0.f, 0.f, 0.f);
  if (wid == 1) {
    b1v.x = bih1[l]       + bhh1[l];
    b1v.y = bih1[l + 64]  + bhh1[l + 64];
    b1v.z = bih1[l + 128] + bhh1[l + 128];
    b1v.w = bih1[l + 192] + bhh1[l + 192];
  }

  // Zero all 4 parities of both h buffers (h0[-1]=h1[-1..]=0).
  if (t < 128) reinterpret_cast<unsigned*>(hb0)[t] = 0u;
  else         reinterpret_cast<unsigned*>(hb1)[t - 128] = 0u;
  float cst0 = 0.f, cst1 = 0.f;
  const float* X0b = X0T + b * G4 + l * 4;

  // Initial frontier: flags[0..31] (32-wide parallel acquire-RMW poll).
  int c_ok;
  {
    if (t < 32) {
      while (__hip_atomic_fetch_add(&flags[t], 0, __ATOMIC_ACQUIRE,
                                    __HIP_MEMORY_SCOPE_AGENT) != MAGIC) {}
    }
    __syncthreads();   // also makes hb0/hb1 zeroing visible
    c_ok = 31;
  }

  // 2-deep X0 prefetch (wave0 consumes).
  float4 xa0 = make_float4(0.f, 0.f, 0.f, 0.f), xa1 = xa0;
  if (wid == 0) {
    xa0 = *reinterpret_cast<const float4*>(X0b + 0 * (BATCH * G4));
    xa1 = *reinterpret_cast<const float4*>(X0b + 1 * (BATCH * G4));
  }

#define LOAD_H8(SRC, RB)                                                       \
  const uint4* hp_ = reinterpret_cast<const uint4*>(&SRC[RB][0]);              \
  const uint4 v0 = hp_[0], v1 = hp_[1], v2 = hp_[2], v3 = hp_[3];              \
  const uint4 v4 = hp_[4], v5 = hp_[5], v6 = hp_[6], v7 = hp_[7]

#define DOT64(G, ACC0)                                                         \
  dot8h(&w[G][24], v6, v7,                                                     \
  dot8h(&w[G][16], v4, v5,                                                     \
  dot8h(&w[G][8],  v2, v3,                                                     \
  dot8h(&w[G][0],  v0, v1, (ACC0)))))

// Interval K (no barrier inside; barrier once per 2 intervals in the loop):
//  wave0: h0[K]   (intra-wave self-loop, bufs (K-1)&3 -> K&3)
//  wave1: SB[K-2] (reads h0[K-2], >=1 epoch old)
//  wave2: h1[K-4] (reads SB[K-4] (>=1 epoch old) + own h1[K-5])
#define INT_STEP(K, XV)                                                        \
  do {                                                                         \
    if (wid == 0) {                                                            \
      if ((K) < SEQ) {                                                         \
        LOAD_H8(hb0, ((K) - 1) & 3);                                           \
        const float A0 = DOT64(0, (XV).x);                                     \
        const float A1 = DOT64(1, (XV).y);                                     \
        const float A2 = DOT64(2, (XV).z);                                     \
        const float A3 = DOT64(3, (XV).w);                                     \
        const float gi = fsigm(A0);                                            \
        const float gf = fsigm(A1);                                            \
        const float gg = ftanh(A2);                                            \
        const float go = fsigm(A3);                                            \
        cst0 = fmaf(gf, cst0, gi * gg);                                        \
        const float hv = go * ftanh(cst0);                                     \
        reinterpret_cast<_Float16*>(&hb0[(K) & 3][0])[l] = (_Float16)hv;       \
      }                                                                        \
    } else if (wid == 1) {                                                     \
      if ((K) >= 2 && (K) <= SEQ + 1) {                                        \
        const int m_ = (K) - 2;                                                \
        LOAD_H8(hb0, m_ & 3);                                                  \
        const float B0 = DOT64(0, b1v.x);                                      \
        const float B1 = DOT64(1, b1v.y);                                      \
        const float B2 = DOT64(2, b1v.z);                                      \
        const float B3 = DOT64(3, b1v.w);                                      \
        SBb[m_ & 3][l] = make_float4(B0, B1, B2, B3);                          \
      }                                                                        \
    } else if (wid == 2) {                                                     \
      if ((K) >= 4) {                                                          \
        const int m_ = (K) - 4;                                                \
        LOAD_H8(hb1, (m_ - 1) & 3);                                            \
        const float C0 = DOT64(0, 0.f);                                        \
        const float C1 = DOT64(1, 0.f);                                        \
        const float C2 = DOT64(2, 0.f);                                        \
        const float C3 = DOT64(3, 0.f);                                        \
        const float4 sb = SBb[m_ & 3][l];                                      \
        const float gi = fsigm(C0 + sb.x);                                     \
        const float gf = fsigm(C1 + sb.y);                                     \
        const float gg = ftanh(C2 + sb.z);                                     \
        const float go = fsigm(C3 + sb.w);                                     \
        cst1 = fmaf(gf, cst1, gi * gg);                                        \
        const float hv = go * ftanh(cst1);                                     \
        reinterpret_cast<_Float16*>(&hb1[m_ & 3][0])[l] = (_Float16)hv;        \
      }                                                                        \
    }                                                                          \
  } while (0)

  for (int k = 0; k < SEQ + 4; k += 2) {   // intervals K=k,k+1 (516 total)
    // Frontier advance: 32-wide batch; wave0 consumes X0[k..k+3].
    if (k + 8 > c_ok && c_ok < 255) {
      const int base = c_ok + 1;
      if (t < 32 && base + t <= 255) {
        while (__hip_atomic_fetch_add(&flags[base + t], 0, __ATOMIC_ACQUIRE,
                                      __HIP_MEMORY_SCOPE_AGENT) != MAGIC) {}
      }
      __syncthreads();
      c_ok = (base + 31 < 255) ? base + 31 : 255;
    }
    if (wid < 3) {
#pragma unroll
      for (int j = 0; j < 4; ++j) {
        half2v* wp = &w[j][0];
        asm volatile("" : "+v"(wp[0]), "+v"(wp[1]), "+v"(wp[2]), "+v"(wp[3]),
                          "+v"(wp[4]), "+v"(wp[5]), "+v"(wp[6]), "+v"(wp[7]));
        asm volatile("" : "+v"(wp[8]), "+v"(wp[9]), "+v"(wp[10]), "+v"(wp[11]),
                          "+v"(wp[12]), "+v"(wp[13]), "+v"(wp[14]), "+v"(wp[15]));
        asm volatile("" : "+v"(wp[16]), "+v"(wp[17]), "+v"(wp[18]), "+v"(wp[19]),
                          "+v"(wp[20]), "+v"(wp[21]), "+v"(wp[22]), "+v"(wp[23]));
        asm volatile("" : "+v"(wp[24]), "+v"(wp[25]), "+v"(wp[26]), "+v"(wp[27]),
                          "+v"(wp[28]), "+v"(wp[29]), "+v"(wp[30]), "+v"(wp[31]));
      }
    }
    // Issue next 2 X0 loads; in flight across the barrier.
    float4 xb0 = xa0, xb1 = xa1;
    if (wid == 0 && k + 2 < SEQ) {
      xb0 = *reinterpret_cast<const float4*>(X0b + (k + 2) * (BATCH * G4));
      xb1 = *reinterpret_cast<const float4*>(X0b + (k + 3) * (BATCH * G4));
    }
    INT_STEP(k,     xa0);
    INT_STEP(k + 1, xa1);
    BAR_LDS();                      // one barrier per epoch (2 intervals)
    xa0 = xb0; xa1 = xb1;
  }
#undef INT_STEP
#undef DOT64
#undef LOAD_H8
  // h1[511] written at interval 515 -> hb1[511 & 3] = hb1[3].

  // wait for this batch's GAT result
  if (t == 0) {
    while (__hip_atomic_fetch_add(&flags[256 + b], 0, __ATOMIC_ACQUIRE,
                                  __HIP_MEMORY_SCOPE_AGENT) != MAGIC) {}
  }
  __syncthreads();

  // ---------------- fused heads: c = [h1(64) | xg_b(1024)] ----------------
  if (t < 64) {
    const _Float16* hh = reinterpret_cast<const _Float16*>(&hb1[3][0]);
    cbuf[t] = (float)hh[t];
  }
  for (int k = t; k < 1024; k += 256) cbuf[64 + k] = xg[b * 1024 + k];
  __syncthreads();
  if (t < 96) {
    const int head = t >> 5, h = t & 31;
    const float* w1 = (head == 0) ? dw1 : (head == 1) ? rw1 : vw1;
    const float* b1 = (head == 0) ? db1 : (head == 1) ? rb1 : vb1;
    float a0 = 0.f, a1v = 0.f, a2v = 0.f, a3v = 0.f;
    for (int k = 0; k < 1088; k += 4) {
      a0  = fmaf(cbuf[k],     w1[k * 32 + h],       a0);
      a1v = fmaf(cbuf[k + 1], w1[(k + 1) * 32 + h], a1v);
      a2v = fmaf(cbuf[k + 2], w1[(k + 2) * 32 + h], a2v);
      a3v = fmaf(cbuf[k + 3], w1[(k + 3) * 32 + h], a3v);
    }
    hidc[head * 32 + h] = fmaxf(b1[h] + ((a0 + a1v) + (a2v + a3v)), 0.f);
  }
  __syncthreads();
  if (t < 4) {
    const int head2 = (t < 2) ? t : 2;
    const int o = (t < 2) ? 0 : (t - 2);
    const int odim = (t < 2) ? 1 : 2;
    const float* w2  = (head2 == 0) ? dw2 : (head2 == 1) ? rw2 : vw2;
    const float* b2p = (head2 == 0) ? db2 : (head2 == 1) ? rb2 : vb2;
    float acc = b2p[o];
    for (int hh = 0; hh < 32; ++hh)
      acc = fmaf(hidc[head2 * 32 + hh], w2[hh * odim + o], acc);
    const int off = (t == 0) ? b : (t == 1) ? (4 + b) : (8 + 2 * b + o);
    out[off] = acc;   // [dir(4) | ret(4) | vol(4x2)] flat
  }
}

// ---------------------------------------------------------------------------
extern "C" void kernel_launch(void* const* d_in, const int* in_sizes, int n_in,
                              void* d_out, int out_size, void* d_ws, size_t ws_size,
                              hipStream_t stream) {
  const float* x     = (const float*)d_in[0];
  const int*   adj   = (const int*)  d_in[1];
  const float* emb_w = (const float*)d_in[2];
  const float* emb_b = (const float*)d_in[3];
  const float* g1W   = (const float*)d_in[4];
  const float* g1a   = (const float*)d_in[5];
  const float* g2W   = (const float*)d_in[6];
  const float* g2a   = (const float*)d_in[7];
  const float* Wih0  = (const float*)d_in[8];
  const float* Whh0  = (const float*)d_in[9];
  const float* bih0  = (const float*)d_in[10];
  const float* bhh0  = (const float*)d_in[11];
  const float* Wih1  = (const float*)d_in[12];
  const float* Whh1  = (const float*)d_in[13];
  const float* bih1  = (const float*)d_in[14];
  const float* bhh1  = (const float*)d_in[15];
  const float* dw1 = (const float*)d_in[16]; const float* db1 = (const float*)d_in[17];
  const float* dw2 = (const float*)d_in[18]; const float* db2 = (const float*)d_in[19];
  const float* rw1 = (const float*)d_in[20]; const float* rb1 = (const float*)d_in[21];
  const float* rw2 = (const float*)d_in[22]; const float* rb2 = (const float*)d_in[23];
  const float* vw1 = (const float*)d_in[24]; const float* vb1 = (const float*)d_in[25];
  const float* vw2 = (const float*)d_in[26]; const float* vb2 = (const float*)d_in[27];

  float* ws = (float*)d_ws;
  float* X0 = ws;                          // SEQ*BATCH*256 floats = 2 MB (transposed)
  float* xg = ws + SEQ * BATCH * G4;       // 4096 floats
  int*  flg = (int*)(xg + BATCH * NN * 8); // 260 flag ints (0xAA-poison = not ready)
  float* out = (float*)d_out;

  hipLaunchKernelGGL(fused_all, dim3(132), dim3(256), 0, stream,
                     x, adj, emb_w, emb_b, g1W, g1a, g2W, g2a,
                     Wih0, Whh0, bih0, bhh0, Wih1, Whh1, bih1, bhh1,
                     dw1, db1, dw2, db2, rw1, rb1, rw2, rb2,
                     vw1, vb1, vw2, vb2,
                     X0, xg, flg, out);
}

// Round 8
// 377.774 us; speedup vs baseline: 1.1789x; 1.0324x over previous
//
#include <hip/hip_runtime.h>

#define SEQ   512
#define BATCH 4
#define NN    128
#define HID   64
#define G4    256   // 4*HID gates per layer
#define MAGIC 0x13579BDF

typedef _Float16 half2v __attribute__((ext_vector_type(2)));

// Fast activations: v_exp_f32 + v_rcp_f32 (abs err ~1e-6, threshold is 1e-3)
__device__ __forceinline__ float frcp(float x)  { return __builtin_amdgcn_rcpf(x); }
__device__ __forceinline__ float fsigm(float x) { return frcp(1.f + __expf(-x)); }
__device__ __forceinline__ float ftanh(float x) { return 1.f - 2.f * frcp(1.f + __expf(2.f * x)); }
__device__ __forceinline__ float lrelu(float x) { return x > 0.f ? x : 0.2f * x; }
__device__ __forceinline__ float dot4f(float4 w, float4 h) {
  return fmaf(w.x, h.x, fmaf(w.y, h.y, fmaf(w.z, h.z, w.w * h.w)));
}
__device__ __forceinline__ void pin4(float4& v) {
  asm volatile("" : "+v"(v.x), "+v"(v.y), "+v"(v.z), "+v"(v.w));
}
__device__ __forceinline__ half2v u2h(unsigned u) {
  return __builtin_bit_cast(half2v, u);
}
// v_dot2_f32_f16: 2 f16 MACs, f32 accumulate (exact products, f32 sum).
__device__ __forceinline__ float fdot2(half2v a, half2v b, float c) {
#if __has_builtin(__builtin_amdgcn_fdot2)
  return __builtin_amdgcn_fdot2(a, b, c, false);
#else
  float d = c;
  asm("v_dot2_f32_f16 %0, %1, %2, %0" : "+v"(d) : "v"(a), "v"(b));
  return d;
#endif
}
// 16-elem f16 dot: 8 chained v_dot2 (w = 8 half2, h = two uint4 of packed f16).
__device__ __forceinline__ float dot8h(const half2v* w, const uint4& a,
                                       const uint4& b, float acc) {
  acc = fdot2(w[0], u2h(a.x), acc);
  acc = fdot2(w[1], u2h(a.y), acc);
  acc = fdot2(w[2], u2h(a.z), acc);
  acc = fdot2(w[3], u2h(a.w), acc);
  acc = fdot2(w[4], u2h(b.x), acc);
  acc = fdot2(w[5], u2h(b.y), acc);
  acc = fdot2(w[6], u2h(b.z), acc);
  acc = fdot2(w[7], u2h(b.w), acc);
  return acc;
}

// LDS-only barrier: s_waitcnt lgkmcnt(0) + s_barrier, NO vmcnt(0) drain.
#define BAR_LDS() asm volatile("s_waitcnt lgkmcnt(0)\n\ts_barrier" ::: "memory")

// ---------------------------------------------------------------------------
// fused_all: ONE kernel, 132 blocks x 256 threads.
//   blocks 0-3   : LSTM scan + heads, gated on banded X0 flags.
//   blocks 4-131 : X0 producer, band-interleaved; blocks 4-7 then GAT.
// R19: epoch = 4 intervals (was 2) with 8-deep buffers -> 130 barriers
//   (was 258); frontier polls moved OFF wave0 onto idle wave3 (lanes
//   192-223); X0 prefetch 4-deep. Schedule:
//     wave0 @K: h0[K]   = gates(Whh0*h0[K-1] + X0[K])   (intra-wave self-loop)
//     wave1 @K: SB[K-4] = Wih1*h0[K-4] + b1             (>=1 epoch behind)
//     wave2 @K: h1[K-8] = gates(SB[K-8] + Whh1*h1[K-9]) (>=1 epoch behind)
//   520 intervals; h1[511] lands in hb1[511&7] = hb1[7].
// ---------------------------------------------------------------------------
__global__ __attribute__((amdgpu_flat_work_group_size(256, 256),
                          amdgpu_waves_per_eu(1, 4)))
void fused_all(
    const float* __restrict__ x, const int* __restrict__ adj,
    const float* __restrict__ emb_w, const float* __restrict__ emb_b,
    const float* __restrict__ W1, const float* __restrict__ a1,
    const float* __restrict__ W2, const float* __restrict__ a2,
    const float* __restrict__ Wih0, const float* __restrict__ Whh0,
    const float* __restrict__ bih0, const float* __restrict__ bhh0,
    const float* __restrict__ Wih1, const float* __restrict__ Whh1,
    const float* __restrict__ bih1, const float* __restrict__ bhh1,
    const float* __restrict__ dw1, const float* __restrict__ db1,
    const float* __restrict__ dw2, const float* __restrict__ db2,
    const float* __restrict__ rw1, const float* __restrict__ rb1,
    const float* __restrict__ rw2, const float* __restrict__ rb2,
    const float* __restrict__ vw1, const float* __restrict__ vb1,
    const float* __restrict__ vw2, const float* __restrict__ vb2,
    float* __restrict__ X0T, float* __restrict__ xg,
    int* __restrict__ flags, float* __restrict__ out)
{
  const int bid = blockIdx.x;
  const int tid = threadIdx.x;

  if (bid >= 4) {
    // =================== PRODUCER: band-interleaved X0 ===================
    const int c = bid - 4;
    __shared__ __align__(16) float xls[NN];
    {
      const int g = tid;                       // one gate per thread
      float4 w4[32];
      {
        const float4* wp = reinterpret_cast<const float4*>(Wih0 + g * NN);
#pragma unroll
        for (int i = 0; i < 32; ++i) w4[i] = wp[i];
#pragma unroll
        for (int i = 0; i < 32; ++i) pin4(w4[i]);
      }
      const float bsum = bih0[g] + bhh0[g];
      for (int phase = 0; phase < 4; ++phase) {
        const int T = c + 128 * phase;
        for (int bb = 0; bb < BATCH; ++bb) {
          if (tid < NN) xls[tid] = x[(bb * SEQ + T) * NN + tid];
          __syncthreads();
          {
            const float4* hp = reinterpret_cast<const float4*>(xls);
            float p0 = 0.f, p1 = 0.f, p2 = 0.f, p3 = 0.f;
#pragma unroll
            for (int k = 0; k < 32; k += 4) {
              p0 += dot4f(w4[k],     hp[k]);
              p1 += dot4f(w4[k + 1], hp[k + 1]);
              p2 += dot4f(w4[k + 2], hp[k + 2]);
              p3 += dot4f(w4[k + 3], hp[k + 3]);
            }
            X0T[(4 * T + bb) * G4 + (g & 63) * 4 + (g >> 6)] =
                ((p0 + p1) + (p2 + p3)) + bsum;
          }
          __syncthreads();   // drains this block's X0 stores before flag release
        }
        if (tid == 0 && phase == 0)
          __hip_atomic_store(&flags[c], MAGIC, __ATOMIC_RELEASE,
                             __HIP_MEMORY_SCOPE_AGENT);
        if (tid == 0 && phase == 3)
          __hip_atomic_store(&flags[128 + c], MAGIC, __ATOMIC_RELEASE,
                             __HIP_MEMORY_SCOPE_AGENT);
      }
    }
    if (bid >= 8) return;

    // =================== GAT (blocks 4-7, batch b) ===================
    const int b = bid - 4;
    __shared__ float adjm[NN * 129];
    __shared__ __align__(16) float gxls[NN];
    __shared__ float u[16], v[16];
    __shared__ float Wh2[NN][9];
    __shared__ float f1b[NN], f2b[NN];
    __shared__ float p[NN];

    for (int idx = tid; idx < NN * NN; idx += 256)
      adjm[(idx >> 7) * 129 + (idx & 127)] = (adj[idx] > 0) ? 1.f : 0.f;
    if (tid < NN) gxls[tid] = x[(b * SEQ + (SEQ - 1)) * NN + tid];
    if (tid < 16) {
      float uu = 0.f, vv = 0.f;
      for (int fp = 0; fp < 16; ++fp) {
        uu += emb_w[fp] * W1[fp * 16 + tid];
        vv += emb_b[fp] * W1[fp * 16 + tid];
      }
      u[tid] = uu; v[tid] = vv;
    }
    __syncthreads();
    float s1 = 0.f, t1 = 0.f, s2 = 0.f, t2 = 0.f;
    for (int f = 0; f < 16; ++f) {
      s1 += u[f] * a1[f];      t1 += v[f] * a1[f];
      s2 += u[f] * a1[16 + f]; t2 += v[f] * a1[16 + f];
    }
    if (tid < NN) {
      const int i = tid;
      const float f1i = gxls[i] * s1 + t1;
      float m = -1e30f;
      for (int j = 0; j < NN; ++j)
        if (adjm[i * 129 + j] != 0.f)
          m = fmaxf(m, lrelu(f1i + gxls[j] * s2 + t2));
      float ssum = 0.f, ps = 0.f;
      for (int j = 0; j < NN; ++j)
        if (adjm[i * 129 + j] != 0.f) {
          const float wgt = __expf(lrelu(f1i + gxls[j] * s2 + t2) - m);
          ssum += wgt; ps += wgt * gxls[j];
        }
      p[i] = ps / ssum;
    }
    __syncthreads();
    if (tid < NN) {
      const int i = tid;
      float xg1[16];
#pragma unroll
      for (int f = 0; f < 16; ++f) {
        const float ov = p[i] * u[f] + v[f];
        xg1[f] = ov > 0.f ? ov : expm1f(ov);
      }
      float wrow[8];
#pragma unroll
      for (int f2 = 0; f2 < 8; ++f2) wrow[f2] = 0.f;
#pragma unroll
      for (int f = 0; f < 16; ++f) {
        const float xv = xg1[f];
#pragma unroll
        for (int f2 = 0; f2 < 8; ++f2) wrow[f2] += xv * W2[f * 8 + f2];
      }
      float fb1 = 0.f, fb2 = 0.f;
#pragma unroll
      for (int f2 = 0; f2 < 8; ++f2) {
        Wh2[i][f2] = wrow[f2];
        fb1 += wrow[f2] * a2[f2];
        fb2 += wrow[f2] * a2[8 + f2];
      }
      f1b[i] = fb1; f2b[i] = fb2;
    }
    __syncthreads();
    if (tid < NN) {
      const int i = tid;
      const float fi = f1b[i];
      float m = -1e30f;
      for (int j = 0; j < NN; ++j)
        if (adjm[i * 129 + j] != 0.f)
          m = fmaxf(m, lrelu(fi + f2b[j]));
      float ssum = 0.f;
      float o[8];
#pragma unroll
      for (int f2 = 0; f2 < 8; ++f2) o[f2] = 0.f;
      for (int j = 0; j < NN; ++j)
        if (adjm[i * 129 + j] != 0.f) {
          const float wgt = __expf(lrelu(fi + f2b[j]) - m);
          ssum += wgt;
#pragma unroll
          for (int f2 = 0; f2 < 8; ++f2) o[f2] += wgt * Wh2[j][f2];
        }
      const float inv = 1.f / ssum;
#pragma unroll
      for (int f2 = 0; f2 < 8; ++f2)
        xg[b * (NN * 8) + i * 8 + f2] = o[f2] * inv;
    }
    __syncthreads();
    if (tid == 0)
      __hip_atomic_store(&flags[256 + b], MAGIC, __ATOMIC_RELEASE,
                         __HIP_MEMORY_SCOPE_AGENT);
    return;
  }

  // =================== CONSUMER: wave-specialized LSTM pipeline ============
  const int b   = bid;
  const int t   = tid;
  const int wid = t >> 6;           // wave role 0..3 (wave3: polls + barriers)
  const int l   = t & 63;           // lane = unit

  // 8-deep packed-f16 h buffers (32 dwords each) + 8-deep SB float4 buffer.
  __shared__ __align__(16) unsigned hb0[8][32];
  __shared__ __align__(16) unsigned hb1[8][32];
  __shared__ __align__(16) float4 SBb[8][64];
  __shared__ float cbuf[1088];
  __shared__ float hidc[96];

  // Full-row f16 weights: 4 gates x 64 dims = 128 dwords (static indexing).
  const float* Wsrc = (wid == 0) ? Whh0 : (wid == 1) ? Wih1 : Whh1;
  half2v w[4][32];
  if (wid < 3) {
#pragma unroll
    for (int j = 0; j < 4; ++j) {
      const float* wr = Wsrc + (l + 64 * j) * HID;
#pragma unroll
      for (int c = 0; c < 16; ++c) {
        const float4 wv = *reinterpret_cast<const float4*>(wr + 4 * c);
        w[j][2 * c]     = half2v{(_Float16)wv.x, (_Float16)wv.y};
        w[j][2 * c + 1] = half2v{(_Float16)wv.z, (_Float16)wv.w};
      }
    }
  }
  // layer-1 bias, folded into wave1's dot accumulators.
  float4 b1v = make_float4(0.f, 0.f, 0.f, 0.f);
  if (wid == 1) {
    b1v.x = bih1[l]       + bhh1[l];
    b1v.y = bih1[l + 64]  + bhh1[l + 64];
    b1v.z = bih1[l + 128] + bhh1[l + 128];
    b1v.w = bih1[l + 192] + bhh1[l + 192];
  }

  // Zero all 8 parities of both h buffers (h0[-1]=h1[-1..]=0).
  reinterpret_cast<unsigned*>(hb0)[t] = 0u;
  reinterpret_cast<unsigned*>(hb1)[t] = 0u;
  float cst0 = 0.f, cst1 = 0.f;
  const float* X0b = X0T + b * G4 + l * 4;

  // Initial frontier: flags[0..31], polled by wave3 lanes (off wave0's chain).
  int c_ok;
  {
    if (t >= 192 && t < 224) {
      while (__hip_atomic_fetch_add(&flags[t - 192], 0, __ATOMIC_ACQUIRE,
                                    __HIP_MEMORY_SCOPE_AGENT) != MAGIC) {}
    }
    __syncthreads();   // also makes hb0/hb1 zeroing visible
    c_ok = 31;
  }

  // 4-deep X0 prefetch (wave0 consumes).
  float4 xa0 = make_float4(0.f, 0.f, 0.f, 0.f), xa1 = xa0, xa2 = xa0, xa3 = xa0;
  if (wid == 0) {
    xa0 = *reinterpret_cast<const float4*>(X0b + 0 * (BATCH * G4));
    xa1 = *reinterpret_cast<const float4*>(X0b + 1 * (BATCH * G4));
    xa2 = *reinterpret_cast<const float4*>(X0b + 2 * (BATCH * G4));
    xa3 = *reinterpret_cast<const float4*>(X0b + 3 * (BATCH * G4));
  }

#define LOAD_H8(SRC, RB)                                                       \
  const uint4* hp_ = reinterpret_cast<const uint4*>(&SRC[RB][0]);              \
  const uint4 v0 = hp_[0], v1 = hp_[1], v2 = hp_[2], v3 = hp_[3];              \
  const uint4 v4 = hp_[4], v5 = hp_[5], v6 = hp_[6], v7 = hp_[7]

#define DOT64(G, ACC0)                                                         \
  dot8h(&w[G][24], v6, v7,                                                     \
  dot8h(&w[G][16], v4, v5,                                                     \
  dot8h(&w[G][8],  v2, v3,                                                     \
  dot8h(&w[G][0],  v0, v1, (ACC0)))))

// Interval K (no barrier inside; one barrier per 4 intervals in the loop):
//  wave0: h0[K]   (intra-wave self-loop, bufs (K-1)&7 -> K&7)
//  wave1: SB[K-4] (reads h0[K-4], >=1 epoch old)
//  wave2: h1[K-8] (reads SB[K-8] (>=1 epoch old) + own h1[K-9])
#define INT_STEP(K, XV)                                                        \
  do {                                                                         \
    if (wid == 0) {                                                            \
      if ((K) < SEQ) {                                                         \
        LOAD_H8(hb0, ((K) - 1) & 7);                                           \
        const float A0 = DOT64(0, (XV).x);                                     \
        const float A1 = DOT64(1, (XV).y);                                     \
        const float A2 = DOT64(2, (XV).z);                                     \
        const float A3 = DOT64(3, (XV).w);                                     \
        const float gi = fsigm(A0);                                            \
        const float gf = fsigm(A1);                                            \
        const float gg = ftanh(A2);                                            \
        const float go = fsigm(A3);                                            \
        cst0 = fmaf(gf, cst0, gi * gg);                                        \
        const float hv = go * ftanh(cst0);                                     \
        reinterpret_cast<_Float16*>(&hb0[(K) & 7][0])[l] = (_Float16)hv;       \
      }                                                                        \
    } else if (wid == 1) {                                                     \
      if ((K) >= 4 && (K) <= SEQ + 3) {                                        \
        const int m_ = (K) - 4;                                                \
        LOAD_H8(hb0, m_ & 7);                                                  \
        const float B0 = DOT64(0, b1v.x);                                      \
        const float B1 = DOT64(1, b1v.y);                                      \
        const float B2 = DOT64(2, b1v.z);                                      \
        const float B3 = DOT64(3, b1v.w);                                      \
        SBb[m_ & 7][l] = make_float4(B0, B1, B2, B3);                          \
      }                                                                        \
    } else if (wid == 2) {                                                     \
      if ((K) >= 8) {                                                          \
        const int m_ = (K) - 8;                                                \
        LOAD_H8(hb1, (m_ - 1) & 7);                                            \
        const float C0 = DOT64(0, 0.f);                                        \
        const float C1 = DOT64(1, 0.f);                                        \
        const float C2 = DOT64(2, 0.f);                                        \
        const float C3 = DOT64(3, 0.f);                                        \
        const float4 sb = SBb[m_ & 7][l];                                      \
        const float gi = fsigm(C0 + sb.x);                                     \
        const float gf = fsigm(C1 + sb.y);                                     \
        const float gg = ftanh(C2 + sb.z);                                     \
        const float go = fsigm(C3 + sb.w);                                     \
        cst1 = fmaf(gf, cst1, gi * gg);                                        \
        const float hv = go * ftanh(cst1);                                     \
        reinterpret_cast<_Float16*>(&hb1[m_ & 7][0])[l] = (_Float16)hv;        \
      }                                                                        \
    }                                                                          \
  } while (0)

  for (int k = 0; k < SEQ + 8; k += 4) {   // intervals K=k..k+3 (520 total)
    // Frontier advance: 32-wide batch on wave3 (lanes 192-223); keeps
    // c_ok >= k+12 > k+7 (this epoch's prefetch reach).
    if (k + 12 > c_ok && c_ok < 255) {
      const int base = c_ok + 1;
      if (t >= 192 && t < 224 && base + (t - 192) <= 255) {
        while (__hip_atomic_fetch_add(&flags[base + (t - 192)], 0,
                                      __ATOMIC_ACQUIRE,
                                      __HIP_MEMORY_SCOPE_AGENT) != MAGIC) {}
      }
      __syncthreads();
      c_ok = (base + 31 < 255) ? base + 31 : 255;
    }
    if (wid < 3) {
#pragma unroll
      for (int j = 0; j < 4; ++j) {
        half2v* wp = &w[j][0];
        asm volatile("" : "+v"(wp[0]), "+v"(wp[1]), "+v"(wp[2]), "+v"(wp[3]),
                          "+v"(wp[4]), "+v"(wp[5]), "+v"(wp[6]), "+v"(wp[7]));
        asm volatile("" : "+v"(wp[8]), "+v"(wp[9]), "+v"(wp[10]), "+v"(wp[11]),
                          "+v"(wp[12]), "+v"(wp[13]), "+v"(wp[14]), "+v"(wp[15]));
        asm volatile("" : "+v"(wp[16]), "+v"(wp[17]), "+v"(wp[18]), "+v"(wp[19]),
                          "+v"(wp[20]), "+v"(wp[21]), "+v"(wp[22]), "+v"(wp[23]));
        asm volatile("" : "+v"(wp[24]), "+v"(wp[25]), "+v"(wp[26]), "+v"(wp[27]),
                          "+v"(wp[28]), "+v"(wp[29]), "+v"(wp[30]), "+v"(wp[31]));
      }
    }
    // Issue next 4 X0 loads; in flight across the barrier.
    float4 xb0 = xa0, xb1 = xa1, xb2 = xa2, xb3 = xa3;
    if (wid == 0 && k + 4 < SEQ) {
      xb0 = *reinterpret_cast<const float4*>(X0b + (k + 4) * (BATCH * G4));
      xb1 = *reinterpret_cast<const float4*>(X0b + (k + 5) * (BATCH * G4));
      xb2 = *reinterpret_cast<const float4*>(X0b + (k + 6) * (BATCH * G4));
      xb3 = *reinterpret_cast<const float4*>(X0b + (k + 7) * (BATCH * G4));
    }
    INT_STEP(k,     xa0);
    INT_STEP(k + 1, xa1);
    INT_STEP(k + 2, xa2);
    INT_STEP(k + 3, xa3);
    BAR_LDS();                      // one barrier per epoch (4 intervals)
    xa0 = xb0; xa1 = xb1; xa2 = xb2; xa3 = xb3;
  }
#undef INT_STEP
#undef DOT64
#undef LOAD_H8
  // h1[511] written at interval 519 -> hb1[511 & 7] = hb1[7].

  // wait for this batch's GAT result
  if (t == 0) {
    while (__hip_atomic_fetch_add(&flags[256 + b], 0, __ATOMIC_ACQUIRE,
                                  __HIP_MEMORY_SCOPE_AGENT) != MAGIC) {}
  }
  __syncthreads();

  // ---------------- fused heads: c = [h1(64) | xg_b(1024)] ----------------
  if (t < 64) {
    const _Float16* hh = reinterpret_cast<const _Float16*>(&hb1[7][0]);
    cbuf[t] = (float)hh[t];
  }
  for (int k = t; k < 1024; k += 256) cbuf[64 + k] = xg[b * 1024 + k];
  __syncthreads();
  if (t < 96) {
    const int head = t >> 5, h = t & 31;
    const float* w1 = (head == 0) ? dw1 : (head == 1) ? rw1 : vw1;
    const float* b1 = (head == 0) ? db1 : (head == 1) ? rb1 : vb1;
    float a0 = 0.f, a1v = 0.f, a2v = 0.f, a3v = 0.f;
    for (int k = 0; k < 1088; k += 4) {
      a0  = fmaf(cbuf[k],     w1[k * 32 + h],       a0);
      a1v = fmaf(cbuf[k + 1], w1[(k + 1) * 32 + h], a1v);
      a2v = fmaf(cbuf[k + 2], w1[(k + 2) * 32 + h], a2v);
      a3v = fmaf(cbuf[k + 3], w1[(k + 3) * 32 + h], a3v);
    }
    hidc[head * 32 + h] = fmaxf(b1[h] + ((a0 + a1v) + (a2v + a3v)), 0.f);
  }
  __syncthreads();
  if (t < 4) {
    const int head2 = (t < 2) ? t : 2;
    const int o = (t < 2) ? 0 : (t - 2);
    const int odim = (t < 2) ? 1 : 2;
    const float* w2  = (head2 == 0) ? dw2 : (head2 == 1) ? rw2 : vw2;
    const float* b2p = (head2 == 0) ? db2 : (head2 == 1) ? rb2 : vb2;
    float acc = b2p[o];
    for (int hh = 0; hh < 32; ++hh)
      acc = fmaf(hidc[head2 * 32 + hh], w2[hh * odim + o], acc);
    const int off = (t == 0) ? b : (t == 1) ? (4 + b) : (8 + 2 * b + o);
    out[off] = acc;   // [dir(4) | ret(4) | vol(4x2)] flat
  }
}

// ---------------------------------------------------------------------------
extern "C" void kernel_launch(void* const* d_in, const int* in_sizes, int n_in,
                              void* d_out, int out_size, void* d_ws, size_t ws_size,
                              hipStream_t stream) {
  const float* x     = (const float*)d_in[0];
  const int*   adj   = (const int*)  d_in[1];
  const float* emb_w = (const float*)d_in[2];
  const float* emb_b = (const float*)d_in[3];
  const float* g1W   = (const float*)d_in[4];
  const float* g1a   = (const float*)d_in[5];
  const float* g2W   = (const float*)d_in[6];
  const float* g2a   = (const float*)d_in[7];
  const float* Wih0  = (const float*)d_in[8];
  const float* Whh0  = (const float*)d_in[9];
  const float* bih0  = (const float*)d_in[10];
  const float* bhh0  = (const float*)d_in[11];
  const float* Wih1  = (const float*)d_in[12];
  const float* Whh1  = (const float*)d_in[13];
  const float* bih1  = (const float*)d_in[14];
  const float* bhh1  = (const float*)d_in[15];
  const float* dw1 = (const float*)d_in[16]; const float* db1 = (const float*)d_in[17];
  const float* dw2 = (const float*)d_in[18]; const float* db2 = (const float*)d_in[19];
  const float* rw1 = (const float*)d_in[20]; const float* rb1 = (const float*)d_in[21];
  const float* rw2 = (const float*)d_in[22]; const float* rb2 = (const float*)d_in[23];
  const float* vw1 = (const float*)d_in[24]; const float* vb1 = (const float*)d_in[25];
  const float* vw2 = (const float*)d_in[26]; const float* vb2 = (const float*)d_in[27];

  float* ws = (float*)d_ws;
  float* X0 = ws;                          // SEQ*BATCH*256 floats = 2 MB (transposed)
  float* xg = ws + SEQ * BATCH * G4;       // 4096 floats
  int*  flg = (int*)(xg + BATCH * NN * 8); // 260 flag ints (0xAA-poison = not ready)
  float* out = (float*)d_out;

  hipLaunchKernelGGL(fused_all, dim3(132), dim3(256), 0, stream,
                     x, adj, emb_w, emb_b, g1W, g1a, g2W, g2a,
                     Wih0, Whh0, bih0, bhh0, Wih1, Whh1, bih1, bhh1,
                     dw1, db1, dw2, db2, rw1, rb1, rw2, rb2,
                     vw1, vb1, vw2, vb2,
                     X0, xg, flg, out);
}